// Round 2
// baseline (657.463 us; speedup 1.0000x reference)
//
#include <hip/hip_runtime.h>

// GCN forward: 3x (GEMM + normalized adjacency aggregate + ReLU) + mean-pool + linear + log_softmax
// N=50000, E=800000, F=H=128, C=10, G=512
// NOTE: harness passes integer inputs as int32 (edge_index, batch are const int*).

#define FEAT 128
#define NCLASS 10

// ---------------- degree count (excluding self loops) ----------------
__global__ void deg_kernel(const int* __restrict__ ei, int* __restrict__ deg, int ne) {
  int e = blockIdx.x * 256 + threadIdx.x;
  if (e >= ne) return;
  int dst = ei[ne + e];
  atomicAdd(&deg[dst], 1);
}

// dis[i] = rsqrt(deg[i] + 1)   (self-loop included; deg+1 >= 1 always)
__global__ void dis_kernel(const int* __restrict__ deg, float* __restrict__ dis, int n) {
  int i = blockIdx.x * 256 + threadIdx.x;
  if (i >= n) return;
  dis[i] = rsqrtf((float)(deg[i] + 1));
}

// single-block exclusive scan: off[i] = sum(deg[0..i-1]); deg[i] overwritten with same
// value to serve as the fill cursor; off[n] = total (== ne).
__global__ void __launch_bounds__(1024) scan_kernel(int* __restrict__ deg,
                                                    int* __restrict__ off, int n) {
  __shared__ int sh[1024];
  __shared__ int carry_s;
  int t = threadIdx.x;
  if (t == 0) carry_s = 0;
  __syncthreads();
  for (int base = 0; base < n; base += 1024) {
    int i = base + t;
    int v = (i < n) ? deg[i] : 0;
    sh[t] = v;
    __syncthreads();
    int x = v;
    for (int d = 1; d < 1024; d <<= 1) {
      int y = (t >= d) ? sh[t - d] : 0;
      __syncthreads();
      x += y;
      sh[t] = x;
      __syncthreads();
    }
    int total = sh[1023];
    int c = carry_s;
    if (i < n) {
      int excl = c + x - v;
      off[i] = excl;
      deg[i] = excl;  // cursor for fill_kernel
    }
    __syncthreads();
    if (t == 0) carry_s = c + total;
    __syncthreads();
  }
  if (t == 0) off[n] = carry_s;
}

// scatter src indices into CSR ordered by dst
__global__ void fill_kernel(const int* __restrict__ ei, int* __restrict__ cur,
                            int* __restrict__ csr, int ne) {
  int e = blockIdx.x * 256 + threadIdx.x;
  if (e >= ne) return;
  int src = ei[e];
  int dst = ei[ne + e];
  int pos = atomicAdd(&cur[dst], 1);
  csr[pos] = src;
}

// Hs = (X @ W) * dis[row]   -- 64 rows x 128 cols per block, W staged in LDS
__global__ void __launch_bounds__(256) gemm_kernel(const float* __restrict__ X,
                                                   const float* __restrict__ W,
                                                   const float* __restrict__ dis,
                                                   float* __restrict__ Hs, int n) {
  __shared__ float ws[FEAT * FEAT];   // 64 KB
  __shared__ float xs[64][132];       // padded, 33.8 KB
  int tid = threadIdx.x;
  int row0 = blockIdx.x * 64;

  const float4* W4 = (const float4*)W;
  float4* ws4 = (float4*)ws;
  for (int i = tid; i < (FEAT * FEAT) / 4; i += 256) ws4[i] = W4[i];

  const float4* X4 = (const float4*)X;
  for (int i = tid; i < 64 * 32; i += 256) {
    int r = i >> 5;
    int c4 = i & 31;
    float4 v = make_float4(0.f, 0.f, 0.f, 0.f);
    int row = row0 + r;
    if (row < n) v = X4[(size_t)row * 32 + c4];
    *(float4*)&xs[r][c4 * 4] = v;
  }
  __syncthreads();

  int c0 = (tid & 31) * 4;
  int rg = tid >> 5;  // 0..7, 8 rows each
  float4 acc[8];
#pragma unroll
  for (int j = 0; j < 8; ++j) acc[j] = make_float4(0.f, 0.f, 0.f, 0.f);

  for (int k4 = 0; k4 < FEAT / 4; ++k4) {
    float4 w0 = *(const float4*)&ws[(k4 * 4 + 0) * FEAT + c0];
    float4 w1 = *(const float4*)&ws[(k4 * 4 + 1) * FEAT + c0];
    float4 w2 = *(const float4*)&ws[(k4 * 4 + 2) * FEAT + c0];
    float4 w3 = *(const float4*)&ws[(k4 * 4 + 3) * FEAT + c0];
#pragma unroll
    for (int j = 0; j < 8; ++j) {
      float4 xv = *(const float4*)&xs[rg * 8 + j][k4 * 4];
      acc[j].x += xv.x * w0.x + xv.y * w1.x + xv.z * w2.x + xv.w * w3.x;
      acc[j].y += xv.x * w0.y + xv.y * w1.y + xv.z * w2.y + xv.w * w3.y;
      acc[j].z += xv.x * w0.z + xv.y * w1.z + xv.z * w2.z + xv.w * w3.z;
      acc[j].w += xv.x * w0.w + xv.y * w1.w + xv.z * w2.w + xv.w * w3.w;
    }
  }

#pragma unroll
  for (int j = 0; j < 8; ++j) {
    int row = row0 + rg * 8 + j;
    if (row < n) {
      float d = dis[row];
      float4 o = make_float4(acc[j].x * d, acc[j].y * d, acc[j].z * d, acc[j].w * d);
      *(float4*)&Hs[(size_t)row * FEAT + c0] = o;
    }
  }
}

// out[i] = relu(dis[i] * (Hs[i] + sum_{e: dst=i} Hs[src_e]) + b)
// one wave per node, lane covers 2 features (float2 = 512B/row per wave)
__global__ void __launch_bounds__(256) agg_kernel(const float* __restrict__ Hs,
                                                  const int* __restrict__ csr,
                                                  const int* __restrict__ off,
                                                  const float* __restrict__ dis,
                                                  const float* __restrict__ b,
                                                  float* __restrict__ out, int n) {
  int wave = threadIdx.x >> 6;
  int lane = threadIdx.x & 63;
  int node = blockIdx.x * 4 + wave;
  if (node >= n) return;
  int s = off[node];
  int e = off[node + 1];
  const float2* H2 = (const float2*)Hs;
  float2 acc = H2[(size_t)node * 64 + lane];  // self-loop term
  for (int k = s; k < e; ++k) {
    int src = csr[k];
    float2 v = H2[(size_t)src * 64 + lane];
    acc.x += v.x;
    acc.y += v.y;
  }
  float d = dis[node];
  float2 bb = ((const float2*)b)[lane];
  float2 o;
  o.x = fmaxf(fmaf(d, acc.x, bb.x), 0.f);
  o.y = fmaxf(fmaf(d, acc.y, bb.y), 0.f);
  ((float2*)out)[(size_t)node * 64 + lane] = o;
}

// graph boundaries from sorted batch: gstart[g] = first node index with batch >= g
__global__ void bounds_kernel(const int* __restrict__ batch, int* __restrict__ gstart,
                              int n, int g) {
  int i = blockIdx.x * 256 + threadIdx.x;
  if (i >= n) return;
  int bi = batch[i];
  int bp = (i == 0) ? -1 : batch[i - 1];
  for (int q = bp + 1; q <= bi; ++q) gstart[q] = i;
  if (i == n - 1) {
    for (int q = bi + 1; q <= g; ++q) gstart[q] = n;
  }
}

// mean-pool per graph + linear(128->10) + log_softmax; one block (128 thr) per graph
__global__ void __launch_bounds__(128) pool_kernel(const float* __restrict__ h,
                                                   const int* __restrict__ gstart,
                                                   const float* __restrict__ lw,
                                                   const float* __restrict__ lb,
                                                   float* __restrict__ out) {
  int g = blockIdx.x;
  int t = threadIdx.x;
  int s = gstart[g];
  int e = gstart[g + 1];
  float acc = 0.f;
  for (int i = s; i < e; ++i) acc += h[(size_t)i * FEAT + t];
  float cnt = (float)(e - s);
  float pooled = acc / fmaxf(cnt, 1.f);
  __shared__ float lds[FEAT];
  __shared__ float logits[NCLASS];
  lds[t] = pooled;
  __syncthreads();
  if (t < NCLASS) {
    float z = lb[t];
    for (int k = 0; k < FEAT; ++k) z += lds[k] * lw[k * NCLASS + t];
    logits[t] = z;
  }
  __syncthreads();
  if (t < NCLASS) {
    float m = logits[0];
#pragma unroll
    for (int c = 1; c < NCLASS; ++c) m = fmaxf(m, logits[c]);
    float ssum = 0.f;
#pragma unroll
    for (int c = 0; c < NCLASS; ++c) ssum += expf(logits[c] - m);
    out[(size_t)g * NCLASS + t] = logits[t] - m - logf(ssum);
  }
}

extern "C" void kernel_launch(void* const* d_in, const int* in_sizes, int n_in,
                              void* d_out, int out_size, void* d_ws, size_t ws_size,
                              hipStream_t stream) {
  const float* x = (const float*)d_in[0];
  const int* ei = (const int*)d_in[1];     // int32 on device
  const int* batch = (const int*)d_in[2];  // int32 on device
  const float* W0 = (const float*)d_in[3];
  const float* b0 = (const float*)d_in[4];
  const float* W1 = (const float*)d_in[5];
  const float* b1 = (const float*)d_in[6];
  const float* W2 = (const float*)d_in[7];
  const float* b2 = (const float*)d_in[8];
  const float* lw = (const float*)d_in[9];
  const float* lb = (const float*)d_in[10];

  int n = in_sizes[2];        // 50000 nodes
  int ne = in_sizes[1] / 2;   // 800000 edges
  int g = out_size / NCLASS;  // 512 graphs

  char* ws = (char*)d_ws;
  size_t p = 0;
  auto alloc = [&](size_t bytes) {
    size_t cur = p;
    p += (bytes + 255) & ~(size_t)255;
    return cur;
  };
  int* off = (int*)(ws + alloc((size_t)(n + 1) * 4));
  int* deg = (int*)(ws + alloc((size_t)n * 4));
  int* csr = (int*)(ws + alloc((size_t)ne * 4));
  int* gstart = (int*)(ws + alloc((size_t)(g + 1) * 4));
  float* dis = (float*)(ws + alloc((size_t)n * 4));
  float* Hs = (float*)(ws + alloc((size_t)n * FEAT * 4));
  float* Hb = (float*)(ws + alloc((size_t)n * FEAT * 4));

  hipMemsetAsync(deg, 0, (size_t)n * 4, stream);
  deg_kernel<<<(ne + 255) / 256, 256, 0, stream>>>(ei, deg, ne);
  dis_kernel<<<(n + 255) / 256, 256, 0, stream>>>(deg, dis, n);
  scan_kernel<<<1, 1024, 0, stream>>>(deg, off, n);
  fill_kernel<<<(ne + 255) / 256, 256, 0, stream>>>(ei, deg, csr, ne);

  const float* in = x;
  const float* Wv[3] = {W0, W1, W2};
  const float* bv[3] = {b0, b1, b2};
  for (int l = 0; l < 3; ++l) {
    gemm_kernel<<<(n + 63) / 64, 256, 0, stream>>>(in, Wv[l], dis, Hs, n);
    agg_kernel<<<(n + 3) / 4, 256, 0, stream>>>(Hs, csr, off, dis, bv[l], Hb, n);
    in = Hb;
  }

  bounds_kernel<<<(n + 255) / 256, 256, 0, stream>>>(batch, gstart, n, g);
  pool_kernel<<<g, 128, 0, stream>>>(Hb, gstart, lw, lb, (float*)d_out);
}

// Round 3
// 350.430 us; speedup vs baseline: 1.8762x; 1.8762x over previous
//
#include <hip/hip_runtime.h>

// GCN forward: 3x (GEMM + normalized adjacency aggregate + ReLU) + mean-pool + linear + log_softmax
// N=50000, E=800000, F=H=128, C=10, G=512
// Round 2: bf16 Hs (half gather traffic), x4-unrolled edge loop (4 gathers in
// flight), W read via L1 instead of LDS (gemm 1->4 blocks/CU), hierarchical scan.

#define FEAT 128
#define NCLASS 10

__device__ inline unsigned short f2bf(float f) {
  unsigned x = __float_as_uint(f);
  return (unsigned short)((x + 0x7fffu + ((x >> 16) & 1u)) >> 16);  // RNE
}
__device__ inline float2 bf2f(unsigned u) {
  float2 r;
  r.x = __uint_as_float(u << 16);
  r.y = __uint_as_float(u & 0xffff0000u);
  return r;
}

// ---------------- degree count (excluding self loops) ----------------
__global__ void deg_kernel(const int* __restrict__ ei, int* __restrict__ deg, int ne) {
  int e = blockIdx.x * 256 + threadIdx.x;
  if (e >= ne) return;
  atomicAdd(&deg[ei[ne + e]], 1);
}

// dis[i] = rsqrt(deg[i] + 1)
__global__ void dis_kernel(const int* __restrict__ deg, float* __restrict__ dis, int n) {
  int i = blockIdx.x * 256 + threadIdx.x;
  if (i >= n) return;
  dis[i] = rsqrtf((float)(deg[i] + 1));
}

// hierarchical scan, step 1: per-1024-block exclusive scan -> off, block totals -> bsum
__global__ void __launch_bounds__(1024) scan1_kernel(const int* __restrict__ deg,
                                                     int* __restrict__ off,
                                                     int* __restrict__ bsum, int n) {
  __shared__ int sh[1024];
  int t = threadIdx.x;
  int i = blockIdx.x * 1024 + t;
  int v = (i < n) ? deg[i] : 0;
  sh[t] = v;
  __syncthreads();
  int x = v;
  for (int d = 1; d < 1024; d <<= 1) {
    int y = (t >= d) ? sh[t - d] : 0;
    __syncthreads();
    x += y;
    sh[t] = x;
    __syncthreads();
  }
  if (i < n) off[i] = x - v;  // local exclusive
  if (t == 1023) bsum[blockIdx.x] = x;
}

// step 2: serial scan of block totals (nb ~ 49)
__global__ void scan2_kernel(int* __restrict__ bsum, int nb) {
  if (threadIdx.x == 0 && blockIdx.x == 0) {
    int c = 0;
    for (int b = 0; b < nb; ++b) {
      int v = bsum[b];
      bsum[b] = c;
      c += v;
    }
  }
}

// step 3: add base, write cursor copy, set off[n]
__global__ void scan3_kernel(int* __restrict__ off, const int* __restrict__ bsum,
                             int* __restrict__ cur, int n, int ne) {
  int i = blockIdx.x * 256 + threadIdx.x;
  if (i < n) {
    int v = off[i] + bsum[i >> 10];
    off[i] = v;
    cur[i] = v;
  }
  if (i == 0) off[n] = ne;
}

// scatter src indices into CSR ordered by dst
__global__ void fill_kernel(const int* __restrict__ ei, int* __restrict__ cur,
                            int* __restrict__ csr, int ne) {
  int e = blockIdx.x * 256 + threadIdx.x;
  if (e >= ne) return;
  int src = ei[e];
  int dst = ei[ne + e];
  int pos = atomicAdd(&cur[dst], 1);
  csr[pos] = src;
}

// Hs(bf16) = (X @ W) * dis[row]  -- 64 rows/block, X tile in LDS (34 KB -> 4 blocks/CU),
// W read through L1 (block-wide reuse of the same 2 KB per k-step)
__global__ void __launch_bounds__(256) gemm_kernel(const float* __restrict__ X,
                                                   const float* __restrict__ W,
                                                   const float* __restrict__ dis,
                                                   unsigned* __restrict__ Hs, int n) {
  __shared__ float xs[64][132];
  int tid = threadIdx.x;
  int row0 = blockIdx.x * 64;

  const float4* X4 = (const float4*)X;
  for (int i = tid; i < 64 * 32; i += 256) {
    int r = i >> 5;
    int c4 = i & 31;
    float4 v = make_float4(0.f, 0.f, 0.f, 0.f);
    int row = row0 + r;
    if (row < n) v = X4[(size_t)row * 32 + c4];
    *(float4*)&xs[r][c4 * 4] = v;
  }
  __syncthreads();

  int c0 = (tid & 31) * 4;
  int rg = tid >> 5;  // 8 rows per thread
  const float4* W4 = (const float4*)W;
  float4 acc[8];
#pragma unroll
  for (int j = 0; j < 8; ++j) acc[j] = make_float4(0.f, 0.f, 0.f, 0.f);

  for (int k4 = 0; k4 < FEAT / 4; ++k4) {
    float4 w0 = W4[(k4 * 4 + 0) * 32 + (c0 >> 2)];
    float4 w1 = W4[(k4 * 4 + 1) * 32 + (c0 >> 2)];
    float4 w2 = W4[(k4 * 4 + 2) * 32 + (c0 >> 2)];
    float4 w3 = W4[(k4 * 4 + 3) * 32 + (c0 >> 2)];
#pragma unroll
    for (int j = 0; j < 8; ++j) {
      float4 xv = *(const float4*)&xs[rg * 8 + j][k4 * 4];
      acc[j].x += xv.x * w0.x + xv.y * w1.x + xv.z * w2.x + xv.w * w3.x;
      acc[j].y += xv.x * w0.y + xv.y * w1.y + xv.z * w2.y + xv.w * w3.y;
      acc[j].z += xv.x * w0.z + xv.y * w1.z + xv.z * w2.z + xv.w * w3.z;
      acc[j].w += xv.x * w0.w + xv.y * w1.w + xv.z * w2.w + xv.w * w3.w;
    }
  }

#pragma unroll
  for (int j = 0; j < 8; ++j) {
    int row = row0 + rg * 8 + j;
    if (row < n) {
      float d = dis[row];
      uint2 o;
      o.x = (unsigned)f2bf(acc[j].x * d) | ((unsigned)f2bf(acc[j].y * d) << 16);
      o.y = (unsigned)f2bf(acc[j].z * d) | ((unsigned)f2bf(acc[j].w * d) << 16);
      *(uint2*)&Hs[row * 64 + (c0 >> 1)] = o;
    }
  }
}

// out[i] = relu(dis[i] * (Hs[i] + sum_{e: dst=i} Hs[src_e]) + b)
// one wave per node; bf16 row = 256 B = 64 lanes x 1 dword; edge loop unrolled x4
__global__ void __launch_bounds__(256) agg_kernel(const unsigned* __restrict__ Hs,
                                                  const int* __restrict__ csr,
                                                  const int* __restrict__ off,
                                                  const float* __restrict__ dis,
                                                  const float* __restrict__ b,
                                                  float* __restrict__ out, int n) {
  int wave = threadIdx.x >> 6;
  int lane = threadIdx.x & 63;
  int node = blockIdx.x * 4 + wave;
  if (node >= n) return;
  int s = off[node];
  int e = off[node + 1];
  float2 a0 = bf2f(Hs[node * 64 + lane]);  // self-loop term
  float2 a1 = make_float2(0.f, 0.f), a2 = make_float2(0.f, 0.f), a3 = make_float2(0.f, 0.f);
  int k = s;
  for (; k + 4 <= e; k += 4) {
    int s0 = csr[k], s1 = csr[k + 1], s2 = csr[k + 2], s3 = csr[k + 3];
    unsigned u0 = Hs[s0 * 64 + lane];
    unsigned u1 = Hs[s1 * 64 + lane];
    unsigned u2 = Hs[s2 * 64 + lane];
    unsigned u3 = Hs[s3 * 64 + lane];
    float2 v0 = bf2f(u0), v1 = bf2f(u1), v2 = bf2f(u2), v3 = bf2f(u3);
    a0.x += v0.x; a0.y += v0.y;
    a1.x += v1.x; a1.y += v1.y;
    a2.x += v2.x; a2.y += v2.y;
    a3.x += v3.x; a3.y += v3.y;
  }
  for (; k < e; ++k) {
    float2 v = bf2f(Hs[csr[k] * 64 + lane]);
    a0.x += v.x;
    a0.y += v.y;
  }
  a0.x += a1.x + a2.x + a3.x;
  a0.y += a1.y + a2.y + a3.y;
  float d = dis[node];
  float2 bb = ((const float2*)b)[lane];
  float2 o;
  o.x = fmaxf(fmaf(d, a0.x, bb.x), 0.f);
  o.y = fmaxf(fmaf(d, a0.y, bb.y), 0.f);
  ((float2*)out)[node * 64 + lane] = o;
}

// graph boundaries from sorted batch
__global__ void bounds_kernel(const int* __restrict__ batch, int* __restrict__ gstart,
                              int n, int g) {
  int i = blockIdx.x * 256 + threadIdx.x;
  if (i >= n) return;
  int bi = batch[i];
  int bp = (i == 0) ? -1 : batch[i - 1];
  for (int q = bp + 1; q <= bi; ++q) gstart[q] = i;
  if (i == n - 1) {
    for (int q = bi + 1; q <= g; ++q) gstart[q] = n;
  }
}

// mean-pool per graph + linear(128->10) + log_softmax; one block (128 thr) per graph
__global__ void __launch_bounds__(128) pool_kernel(const float* __restrict__ h,
                                                   const int* __restrict__ gstart,
                                                   const float* __restrict__ lw,
                                                   const float* __restrict__ lb,
                                                   float* __restrict__ out) {
  int g = blockIdx.x;
  int t = threadIdx.x;
  int s = gstart[g];
  int e = gstart[g + 1];
  float a0 = 0.f, a1 = 0.f, a2 = 0.f, a3 = 0.f;
  int i = s;
  for (; i + 4 <= e; i += 4) {
    a0 += h[(size_t)i * FEAT + t];
    a1 += h[(size_t)(i + 1) * FEAT + t];
    a2 += h[(size_t)(i + 2) * FEAT + t];
    a3 += h[(size_t)(i + 3) * FEAT + t];
  }
  for (; i < e; ++i) a0 += h[(size_t)i * FEAT + t];
  float acc = a0 + a1 + a2 + a3;
  float cnt = (float)(e - s);
  float pooled = acc / fmaxf(cnt, 1.f);
  __shared__ float lds[FEAT];
  __shared__ float logits[NCLASS];
  lds[t] = pooled;
  __syncthreads();
  if (t < NCLASS) {
    float z = lb[t];
    for (int k = 0; k < FEAT; ++k) z += lds[k] * lw[k * NCLASS + t];
    logits[t] = z;
  }
  __syncthreads();
  if (t < NCLASS) {
    float m = logits[0];
#pragma unroll
    for (int c = 1; c < NCLASS; ++c) m = fmaxf(m, logits[c]);
    float ssum = 0.f;
#pragma unroll
    for (int c = 0; c < NCLASS; ++c) ssum += expf(logits[c] - m);
    out[(size_t)g * NCLASS + t] = logits[t] - m - logf(ssum);
  }
}

extern "C" void kernel_launch(void* const* d_in, const int* in_sizes, int n_in,
                              void* d_out, int out_size, void* d_ws, size_t ws_size,
                              hipStream_t stream) {
  const float* x = (const float*)d_in[0];
  const int* ei = (const int*)d_in[1];
  const int* batch = (const int*)d_in[2];
  const float* W0 = (const float*)d_in[3];
  const float* b0 = (const float*)d_in[4];
  const float* W1 = (const float*)d_in[5];
  const float* b1 = (const float*)d_in[6];
  const float* W2 = (const float*)d_in[7];
  const float* b2 = (const float*)d_in[8];
  const float* lw = (const float*)d_in[9];
  const float* lb = (const float*)d_in[10];

  int n = in_sizes[2];        // 50000 nodes
  int ne = in_sizes[1] / 2;   // 800000 edges
  int g = out_size / NCLASS;  // 512 graphs
  int nb = (n + 1023) / 1024;

  char* ws = (char*)d_ws;
  size_t p = 0;
  auto alloc = [&](size_t bytes) {
    size_t cur = p;
    p += (bytes + 255) & ~(size_t)255;
    return cur;
  };
  int* off = (int*)(ws + alloc((size_t)(n + 1) * 4));
  int* deg = (int*)(ws + alloc((size_t)n * 4));
  int* csr = (int*)(ws + alloc((size_t)ne * 4));
  int* bsum = (int*)(ws + alloc((size_t)nb * 4));
  int* gstart = (int*)(ws + alloc((size_t)(g + 1) * 4));
  float* dis = (float*)(ws + alloc((size_t)n * 4));
  unsigned* Hs = (unsigned*)(ws + alloc((size_t)n * 64 * 4));  // bf16 [n][128]
  float* Hb = (float*)(ws + alloc((size_t)n * FEAT * 4));

  hipMemsetAsync(deg, 0, (size_t)n * 4, stream);
  deg_kernel<<<(ne + 255) / 256, 256, 0, stream>>>(ei, deg, ne);
  dis_kernel<<<(n + 255) / 256, 256, 0, stream>>>(deg, dis, n);
  scan1_kernel<<<nb, 1024, 0, stream>>>(deg, off, bsum, n);
  scan2_kernel<<<1, 64, 0, stream>>>(bsum, nb);
  scan3_kernel<<<(n + 255) / 256, 256, 0, stream>>>(off, bsum, deg, n, ne);
  fill_kernel<<<(ne + 255) / 256, 256, 0, stream>>>(ei, deg, csr, ne);

  const float* in = x;
  const float* Wv[3] = {W0, W1, W2};
  const float* bv[3] = {b0, b1, b2};
  for (int l = 0; l < 3; ++l) {
    gemm_kernel<<<(n + 63) / 64, 256, 0, stream>>>(in, Wv[l], dis, Hs, n);
    agg_kernel<<<(n + 3) / 4, 256, 0, stream>>>(Hs, csr, off, dis, bv[l], Hb, n);
    in = Hb;
  }

  bounds_kernel<<<(n + 255) / 256, 256, 0, stream>>>(batch, gstart, n, g);
  pool_kernel<<<g, 128, 0, stream>>>(Hb, gstart, lw, lb, (float*)d_out);
}

// Round 4
// 321.122 us; speedup vs baseline: 2.0474x; 1.0913x over previous
//
#include <hip/hip_runtime.h>
#include <hip/hip_fp16.h>

// GCN forward: 3x (MFMA GEMM + normalized adjacency aggregate + ReLU) + mean-pool + linear + log_softmax
// N=50000, E=800000, F=H=128, C=10, G=512
// Round 4: f16 MFMA GEMM (Wt transposed, L1-served B-frags, LDS epilogue),
// 2-pass bucketed CSR build (kills 52MB scattered-write amplification),
// fp16 feature buffers end-to-end (better accuracy than bf16 + half traffic).

#define FEAT 128
#define NCLASS 10

typedef _Float16 h8 __attribute__((ext_vector_type(8)));
typedef float f4 __attribute__((ext_vector_type(4)));

__device__ inline float2 h2f2(unsigned u) {
  __half2 h = *reinterpret_cast<__half2*>(&u);
  float2 r;
  r.x = __low2float(h);
  r.y = __high2float(h);
  return r;
}
__device__ inline unsigned f2h2(float a, float b) {
  __half2 h = __floats2half2_rn(a, b);
  return *reinterpret_cast<unsigned*>(&h);
}

// ---- deg count + coarse dst-bucket histogram (LDS-privatized) ----
__global__ void __launch_bounds__(256) deg_hist_kernel(const int* __restrict__ ei,
                                                       int* __restrict__ deg,
                                                       int* __restrict__ bhist,
                                                       int ne, int nb) {
  __shared__ int lh[512];
  int t = threadIdx.x;
  for (int i = t; i < nb; i += 256) lh[i] = 0;
  __syncthreads();
  int e0 = blockIdx.x * 1024 + t;
#pragma unroll
  for (int q = 0; q < 4; ++q) {
    int e = e0 + q * 256;
    if (e < ne) {
      int d = ei[ne + e];
      atomicAdd(&deg[d], 1);
      atomicAdd(&lh[d >> 7], 1);
    }
  }
  __syncthreads();
  for (int i = t; i < nb; i += 256)
    if (lh[i]) atomicAdd(&bhist[i], lh[i]);
}

// dis[i] = rsqrt(deg[i] + 1)
__global__ void dis_kernel(const int* __restrict__ deg, float* __restrict__ dis, int n) {
  int i = blockIdx.x * 256 + threadIdx.x;
  if (i >= n) return;
  dis[i] = rsqrtf((float)(deg[i] + 1));
}

// hierarchical scan over node degrees
__global__ void __launch_bounds__(1024) scan1_kernel(const int* __restrict__ deg,
                                                     int* __restrict__ off,
                                                     int* __restrict__ bsum, int n) {
  __shared__ int sh[1024];
  int t = threadIdx.x;
  int i = blockIdx.x * 1024 + t;
  int v = (i < n) ? deg[i] : 0;
  sh[t] = v;
  __syncthreads();
  int x = v;
  for (int d = 1; d < 1024; d <<= 1) {
    int y = (t >= d) ? sh[t - d] : 0;
    __syncthreads();
    x += y;
    sh[t] = x;
    __syncthreads();
  }
  if (i < n) off[i] = x - v;
  if (t == 1023) bsum[blockIdx.x] = x;
}

__global__ void scan2_kernel(int* __restrict__ bsum, int nbk) {
  if (threadIdx.x == 0 && blockIdx.x == 0) {
    int c = 0;
    for (int b = 0; b < nbk; ++b) {
      int v = bsum[b];
      bsum[b] = c;
      c += v;
    }
  }
}

__global__ void scan3_kernel(int* __restrict__ off, const int* __restrict__ bsum,
                             int* __restrict__ cur, int n, int ne) {
  int i = blockIdx.x * 256 + threadIdx.x;
  if (i < n) {
    int v = off[i] + bsum[i >> 10];
    off[i] = v;
    cur[i] = v;
  }
  if (i == 0) off[n] = ne;
}

// exclusive scan of bucket counts -> bcur (single block, nb <= 512)
__global__ void __launch_bounds__(512) bscan_kernel(const int* __restrict__ bhist,
                                                    int* __restrict__ bcur, int nb) {
  __shared__ int sh[512];
  int t = threadIdx.x;
  int v = (t < nb) ? bhist[t] : 0;
  sh[t] = v;
  __syncthreads();
  int x = v;
  for (int d = 1; d < 512; d <<= 1) {
    int y = (t >= d) ? sh[t - d] : 0;
    __syncthreads();
    x += y;
    sh[t] = x;
    __syncthreads();
  }
  if (t < nb) bcur[t] = x - v;
}

// pass 1: scatter edges into dst-buckets; per-block LDS histogram reserves
// consecutive ranges so bucket writes are short sequential runs.
__global__ void __launch_bounds__(256) scatter1_kernel(const int* __restrict__ ei,
                                                       int* __restrict__ bcur,
                                                       uint2* __restrict__ buf,
                                                       int ne, int nb) {
  __shared__ int lh[512], lbs[512], lc[512];
  int t = threadIdx.x;
  for (int i = t; i < nb; i += 256) {
    lh[i] = 0;
    lc[i] = 0;
  }
  __syncthreads();
  int e0 = blockIdx.x * 1024 + t;
  int srcs[4], dsts[4];
#pragma unroll
  for (int q = 0; q < 4; ++q) {
    int e = e0 + q * 256;
    if (e < ne) {
      srcs[q] = ei[e];
      dsts[q] = ei[ne + e];
      atomicAdd(&lh[dsts[q] >> 7], 1);
    } else {
      dsts[q] = -1;
    }
  }
  __syncthreads();
  for (int i = t; i < nb; i += 256)
    if (lh[i]) lbs[i] = atomicAdd(&bcur[i], lh[i]);
  __syncthreads();
#pragma unroll
  for (int q = 0; q < 4; ++q) {
    if (dsts[q] >= 0) {
      int b = dsts[q] >> 7;
      int p = lbs[b] + atomicAdd(&lc[b], 1);
      buf[p] = make_uint2((unsigned)srcs[q], (unsigned)dsts[q]);
    }
  }
}

// pass 2: bucket-grouped edges -> csr; dst spans 128 nodes per bucket so
// csr writes land in a small window (full-line utilization).
__global__ void fill2_kernel(const uint2* __restrict__ buf, int* __restrict__ cur,
                             int* __restrict__ csr, int ne) {
  int e = blockIdx.x * 256 + threadIdx.x;
  if (e >= ne) return;
  uint2 v = buf[e];
  int pos = atomicAdd(&cur[v.y], 1);
  csr[pos] = (int)v.x;
}

// convert 3 weight matrices to f16 transposed: Wt[l][n][k] = W_l[k][n]
__global__ void wtcvt_kernel(const float* __restrict__ W0, const float* __restrict__ W1,
                             const float* __restrict__ W2, _Float16* __restrict__ Wt) {
  int i = blockIdx.x * 256 + threadIdx.x;
  if (i >= 3 * FEAT * FEAT) return;
  int l = i / (FEAT * FEAT);
  int r = i - l * (FEAT * FEAT);
  int nn = r >> 7, kk = r & 127;
  const float* W = (l == 0) ? W0 : (l == 1) ? W1 : W2;
  Wt[i] = (_Float16)W[kk * FEAT + nn];
}

// Hs(f16) = (X @ W) * dis[row] via v_mfma_f32_16x16x32_f16
// block = 256 thr = 4 waves, 64 rows/block; Wt read through L1 (32 KB, block-wide reuse)
template <bool F32IN>
__global__ void __launch_bounds__(256) gemm_mfma_kernel(const void* __restrict__ Xin,
                                                        const _Float16* __restrict__ Wt,
                                                        const float* __restrict__ dis,
                                                        _Float16* __restrict__ Hs, int n) {
  __shared__ _Float16 st[64 * FEAT];  // 16 KB epilogue staging
  int tid = threadIdx.x;
  int w = tid >> 6, lane = tid & 63;
  int l15 = lane & 15, hi = lane >> 4;

  int rowA = blockIdx.x * 64 + w * 16 + l15;
  int rA = min(rowA, n - 1);
  const _Float16* Xh = (const _Float16*)Xin;
  const float* Xf = (const float*)Xin;

  f4 acc[8];
#pragma unroll
  for (int nb = 0; nb < 8; ++nb) acc[nb] = (f4)(0.f);

#pragma unroll
  for (int kk = 0; kk < FEAT; kk += 32) {
    int ko = kk + hi * 8;
    h8 a;
    if (F32IN) {
      float4 x0 = *(const float4*)&Xf[(size_t)rA * FEAT + ko];
      float4 x1 = *(const float4*)&Xf[(size_t)rA * FEAT + ko + 4];
      a[0] = (_Float16)x0.x; a[1] = (_Float16)x0.y; a[2] = (_Float16)x0.z; a[3] = (_Float16)x0.w;
      a[4] = (_Float16)x1.x; a[5] = (_Float16)x1.y; a[6] = (_Float16)x1.z; a[7] = (_Float16)x1.w;
    } else {
      a = *(const h8*)&Xh[(size_t)rA * FEAT + ko];
    }
#pragma unroll
    for (int nb = 0; nb < 8; ++nb) {
      h8 b = *(const h8*)&Wt[(nb * 16 + l15) * FEAT + ko];
      acc[nb] = __builtin_amdgcn_mfma_f32_16x16x32_f16(a, b, acc[nb], 0, 0, 0);
    }
  }

  // D: row=(lane>>4)*4+r, col=lane&15  -> scale by dis, stage f16 in LDS
  float dv[4];
#pragma unroll
  for (int r = 0; r < 4; ++r) {
    int grow = blockIdx.x * 64 + w * 16 + hi * 4 + r;
    dv[r] = dis[min(grow, n - 1)];
  }
#pragma unroll
  for (int nb = 0; nb < 8; ++nb)
#pragma unroll
    for (int r = 0; r < 4; ++r)
      st[(w * 16 + hi * 4 + r) * FEAT + nb * 16 + l15] = (_Float16)(acc[nb][r] * dv[r]);
  __syncthreads();

  // coalesced copy LDS -> global (16 KB)
  int rowbase = blockIdx.x * 64;
#pragma unroll
  for (int i = tid; i < 64 * FEAT / 8; i += 256) {
    int row = rowbase + (i >> 4);
    if (row < n)
      *(uint4*)&Hs[(size_t)row * FEAT + (i & 15) * 8] = *(const uint4*)&st[(i >> 4) * FEAT + (i & 15) * 8];
  }
}

// out(f16) = relu(dis[i] * (Hs[i] + sum_{e: dst=i} Hs[src_e]) + b)
// one wave per node; f16 row = 256 B = 64 lanes x 1 dword; edge loop unrolled x4
__global__ void __launch_bounds__(256) agg_kernel(const unsigned* __restrict__ Hs,
                                                  const int* __restrict__ csr,
                                                  const int* __restrict__ off,
                                                  const float* __restrict__ dis,
                                                  const float* __restrict__ b,
                                                  unsigned* __restrict__ out, int n) {
  int wave = threadIdx.x >> 6;
  int lane = threadIdx.x & 63;
  int node = blockIdx.x * 4 + wave;
  if (node >= n) return;
  int s = off[node];
  int e = off[node + 1];
  float2 a0 = h2f2(Hs[node * 64 + lane]);  // self-loop term
  float2 a1 = make_float2(0.f, 0.f), a2 = make_float2(0.f, 0.f), a3 = make_float2(0.f, 0.f);
  int k = s;
  for (; k + 4 <= e; k += 4) {
    int s0 = csr[k], s1 = csr[k + 1], s2 = csr[k + 2], s3 = csr[k + 3];
    unsigned u0 = Hs[s0 * 64 + lane];
    unsigned u1 = Hs[s1 * 64 + lane];
    unsigned u2 = Hs[s2 * 64 + lane];
    unsigned u3 = Hs[s3 * 64 + lane];
    float2 v0 = h2f2(u0), v1 = h2f2(u1), v2 = h2f2(u2), v3 = h2f2(u3);
    a0.x += v0.x; a0.y += v0.y;
    a1.x += v1.x; a1.y += v1.y;
    a2.x += v2.x; a2.y += v2.y;
    a3.x += v3.x; a3.y += v3.y;
  }
  for (; k < e; ++k) {
    float2 v = h2f2(Hs[csr[k] * 64 + lane]);
    a0.x += v.x;
    a0.y += v.y;
  }
  a0.x += a1.x + a2.x + a3.x;
  a0.y += a1.y + a2.y + a3.y;
  float d = dis[node];
  float2 bb = ((const float2*)b)[lane];
  float ox = fmaxf(fmaf(d, a0.x, bb.x), 0.f);
  float oy = fmaxf(fmaf(d, a0.y, bb.y), 0.f);
  out[node * 64 + lane] = f2h2(ox, oy);
}

// graph boundaries from sorted batch
__global__ void bounds_kernel(const int* __restrict__ batch, int* __restrict__ gstart,
                              int n, int g) {
  int i = blockIdx.x * 256 + threadIdx.x;
  if (i >= n) return;
  int bi = batch[i];
  int bp = (i == 0) ? -1 : batch[i - 1];
  for (int q = bp + 1; q <= bi; ++q) gstart[q] = i;
  if (i == n - 1) {
    for (int q = bi + 1; q <= g; ++q) gstart[q] = n;
  }
}

// mean-pool per graph (f16 input) + linear(128->10) + log_softmax
__global__ void __launch_bounds__(128) pool_kernel(const __half* __restrict__ h,
                                                   const int* __restrict__ gstart,
                                                   const float* __restrict__ lw,
                                                   const float* __restrict__ lb,
                                                   float* __restrict__ out) {
  int g = blockIdx.x;
  int t = threadIdx.x;
  int s = gstart[g];
  int e = gstart[g + 1];
  float a0 = 0.f, a1 = 0.f, a2 = 0.f, a3 = 0.f;
  int i = s;
  for (; i + 4 <= e; i += 4) {
    a0 += __half2float(h[(size_t)i * FEAT + t]);
    a1 += __half2float(h[(size_t)(i + 1) * FEAT + t]);
    a2 += __half2float(h[(size_t)(i + 2) * FEAT + t]);
    a3 += __half2float(h[(size_t)(i + 3) * FEAT + t]);
  }
  for (; i < e; ++i) a0 += __half2float(h[(size_t)i * FEAT + t]);
  float acc = a0 + a1 + a2 + a3;
  float cnt = (float)(e - s);
  float pooled = acc / fmaxf(cnt, 1.f);
  __shared__ float lds[FEAT];
  __shared__ float logits[NCLASS];
  lds[t] = pooled;
  __syncthreads();
  if (t < NCLASS) {
    float z = lb[t];
    for (int k = 0; k < FEAT; ++k) z += lds[k] * lw[k * NCLASS + t];
    logits[t] = z;
  }
  __syncthreads();
  if (t < NCLASS) {
    float m = logits[0];
#pragma unroll
    for (int c = 1; c < NCLASS; ++c) m = fmaxf(m, logits[c]);
    float ssum = 0.f;
#pragma unroll
    for (int c = 0; c < NCLASS; ++c) ssum += expf(logits[c] - m);
    out[(size_t)g * NCLASS + t] = logits[t] - m - logf(ssum);
  }
}

extern "C" void kernel_launch(void* const* d_in, const int* in_sizes, int n_in,
                              void* d_out, int out_size, void* d_ws, size_t ws_size,
                              hipStream_t stream) {
  const float* x = (const float*)d_in[0];
  const int* ei = (const int*)d_in[1];
  const int* batch = (const int*)d_in[2];
  const float* W0 = (const float*)d_in[3];
  const float* b0 = (const float*)d_in[4];
  const float* W1 = (const float*)d_in[5];
  const float* b1 = (const float*)d_in[6];
  const float* W2 = (const float*)d_in[7];
  const float* b2 = (const float*)d_in[8];
  const float* lw = (const float*)d_in[9];
  const float* lb = (const float*)d_in[10];

  int n = in_sizes[2];        // 50000 nodes
  int ne = in_sizes[1] / 2;   // 800000 edges
  int g = out_size / NCLASS;  // 512 graphs
  int nbk = (n + 1023) / 1024;      // scan blocks
  int nb = (n + 127) >> 7;          // dst buckets (~391)

  char* ws = (char*)d_ws;
  size_t p = 0;
  auto alloc = [&](size_t bytes) {
    size_t cur = p;
    p += (bytes + 255) & ~(size_t)255;
    return cur;
  };
  int* off = (int*)(ws + alloc((size_t)(n + 1) * 4));
  int* deg = (int*)(ws + alloc((size_t)n * 4));
  int* csr = (int*)(ws + alloc((size_t)ne * 4));
  int* bsum = (int*)(ws + alloc((size_t)nbk * 4));
  int* bhist = (int*)(ws + alloc((size_t)512 * 4));
  int* bcur = (int*)(ws + alloc((size_t)512 * 4));
  int* gstart = (int*)(ws + alloc((size_t)(g + 1) * 4));
  float* dis = (float*)(ws + alloc((size_t)n * 4));
  uint2* buf = (uint2*)(ws + alloc((size_t)ne * 8));
  _Float16* Wt = (_Float16*)(ws + alloc((size_t)3 * FEAT * FEAT * 2));
  _Float16* Hs = (_Float16*)(ws + alloc((size_t)n * FEAT * 2));
  _Float16* Hb = (_Float16*)(ws + alloc((size_t)n * FEAT * 2));

  hipMemsetAsync(deg, 0, (size_t)n * 4, stream);
  hipMemsetAsync(bhist, 0, 512 * 4, stream);

  deg_hist_kernel<<<(ne + 1023) / 1024, 256, 0, stream>>>(ei, deg, bhist, ne, nb);
  dis_kernel<<<(n + 255) / 256, 256, 0, stream>>>(deg, dis, n);
  scan1_kernel<<<nbk, 1024, 0, stream>>>(deg, off, bsum, n);
  scan2_kernel<<<1, 64, 0, stream>>>(bsum, nbk);
  scan3_kernel<<<(n + 255) / 256, 256, 0, stream>>>(off, bsum, deg, n, ne);
  bscan_kernel<<<1, 512, 0, stream>>>(bhist, bcur, nb);
  scatter1_kernel<<<(ne + 1023) / 1024, 256, 0, stream>>>(ei, bcur, buf, ne, nb);
  fill2_kernel<<<(ne + 255) / 256, 256, 0, stream>>>(buf, deg, csr, ne);
  wtcvt_kernel<<<(3 * FEAT * FEAT + 255) / 256, 256, 0, stream>>>(W0, W1, W2, Wt);

  const float* bv[3] = {b0, b1, b2};
  for (int l = 0; l < 3; ++l) {
    const void* in = (l == 0) ? (const void*)x : (const void*)Hb;
    const _Float16* wt = Wt + (size_t)l * FEAT * FEAT;
    if (l == 0)
      gemm_mfma_kernel<true><<<(n + 63) / 64, 256, 0, stream>>>(in, wt, dis, Hs, n);
    else
      gemm_mfma_kernel<false><<<(n + 63) / 64, 256, 0, stream>>>(in, wt, dis, Hs, n);
    agg_kernel<<<(n + 3) / 4, 256, 0, stream>>>((const unsigned*)Hs, csr, off, dis, bv[l],
                                                (unsigned*)Hb, n);
  }

  bounds_kernel<<<(n + 255) / 256, 256, 0, stream>>>(batch, gstart, n, g);
  pool_kernel<<<g, 128, 0, stream>>>((const __half*)Hb, gstart, lw, lb, (float*)d_out);
}

// Round 5
// 233.935 us; speedup vs baseline: 2.8105x; 1.3727x over previous
//
#include <hip/hip_runtime.h>
#include <hip/hip_fp16.h>

// GCN forward: 3x (MFMA GEMM + normalized adjacency aggregate + ReLU) + mean-pool + linear + log_softmax
// N=50000, E=800000, F=H=128, C=10, G=512
// Round 5: bucket-local CSR build — one block per 128-node bucket computes
// deg/dis/off/csr with LDS atomics only (kills 800k global deg atomics + 50k scan
// + 800k cursor atomics that made deg_hist/fill the top dispatches).

#define FEAT 128
#define NCLASS 10
#define NB_MAX 512  // max dst buckets (n <= 65536 here: 391)

typedef _Float16 h8 __attribute__((ext_vector_type(8)));
typedef float f4 __attribute__((ext_vector_type(4)));

__device__ inline float2 h2f2(unsigned u) {
  __half2 h = *reinterpret_cast<__half2*>(&u);
  float2 r;
  r.x = __low2float(h);
  r.y = __high2float(h);
  return r;
}
__device__ inline unsigned f2h2(float a, float b) {
  __half2 h = __floats2half2_rn(a, b);
  return *reinterpret_cast<unsigned*>(&h);
}

// ---- pass 0: bucket histogram of dst>>7 (grid-stride, LDS-privatized) ----
__global__ void __launch_bounds__(256) hist_kernel(const int* __restrict__ ei,
                                                   int* __restrict__ bhist,
                                                   int ne, int nb, int epb) {
  __shared__ int lh[NB_MAX];
  int t = threadIdx.x;
  for (int i = t; i < nb; i += 256) lh[i] = 0;
  __syncthreads();
  int r0 = blockIdx.x * epb;
  int r1 = min(r0 + epb, ne);
  for (int k = r0 + t; k < r1; k += 256) atomicAdd(&lh[ei[ne + k] >> 7], 1);
  __syncthreads();
  for (int i = t; i < nb; i += 256)
    if (lh[i]) atomicAdd(&bhist[i], lh[i]);
}

// ---- exclusive scan of bucket counts -> bstart (kept) and bcur (consumed) ----
__global__ void __launch_bounds__(512) bscan_kernel(const int* __restrict__ bhist,
                                                    int* __restrict__ bstart,
                                                    int* __restrict__ bcur,
                                                    int* __restrict__ off,
                                                    int nb, int n, int ne) {
  __shared__ int sh[512];
  int t = threadIdx.x;
  int v = (t < nb) ? bhist[t] : 0;
  sh[t] = v;
  __syncthreads();
  int x = v;
  for (int d = 1; d < 512; d <<= 1) {
    int y = (t >= d) ? sh[t - d] : 0;
    __syncthreads();
    x += y;
    sh[t] = x;
    __syncthreads();
  }
  if (t < nb) {
    bstart[t] = x - v;
    bcur[t] = x - v;
  }
  if (t == 0) {
    bstart[nb] = ne;
    off[n] = ne;
  }
}

// ---- pass 1: scatter packed (dst&127,src) into dst-buckets ----
// per-block LDS histogram reserves consecutive ranges -> sequential-ish writes
__global__ void __launch_bounds__(256) scatter_kernel(const int* __restrict__ ei,
                                                      int* __restrict__ bcur,
                                                      unsigned* __restrict__ buf,
                                                      int ne, int nb, int epb) {
  __shared__ int lh[NB_MAX], lbs[NB_MAX];
  int t = threadIdx.x;
  for (int i = t; i < nb; i += 256) lh[i] = 0;
  __syncthreads();
  int r0 = blockIdx.x * epb;
  int r1 = min(r0 + epb, ne);
  for (int k = r0 + t; k < r1; k += 256) atomicAdd(&lh[ei[ne + k] >> 7], 1);
  __syncthreads();
  for (int i = t; i < nb; i += 256) {
    int c = lh[i];
    lbs[i] = c ? atomicAdd(&bcur[i], c) : 0;
    lh[i] = 0;  // reuse as local cursor
  }
  __syncthreads();
  for (int k = r0 + t; k < r1; k += 256) {
    int src = ei[k];
    int dst = ei[ne + k];
    int b = dst >> 7;
    int p = lbs[b] + atomicAdd(&lh[b], 1);
    buf[p] = (unsigned)src | ((unsigned)(dst & 127) << 25);
  }
}

// ---- pass 2: one block per bucket: LDS count -> scan -> dis/off/csr ----
__global__ void __launch_bounds__(256) bucket_build_kernel(const unsigned* __restrict__ buf,
                                                           const int* __restrict__ bstart,
                                                           int* __restrict__ off,
                                                           int* __restrict__ csr,
                                                           float* __restrict__ dis, int n) {
  __shared__ int cnt[128], cur[128], sh[128];
  int b = blockIdx.x, t = threadIdx.x;
  int e0 = bstart[b], e1 = bstart[b + 1];
  if (t < 128) cnt[t] = 0;
  __syncthreads();
  for (int k = e0 + t; k < e1; k += 256) atomicAdd(&cnt[buf[k] >> 25], 1);
  __syncthreads();
  int v = (t < 128) ? cnt[t] : 0;
  if (t < 128) sh[t] = v;
  __syncthreads();
  int x = v;
  for (int d = 1; d < 128; d <<= 1) {
    int y = (t < 128 && t >= d) ? sh[t - d] : 0;
    __syncthreads();
    if (t < 128) {
      x += y;
      sh[t] = x;
    }
    __syncthreads();
  }
  if (t < 128) {
    int node = (b << 7) + t;
    cur[t] = x - v;
    if (node < n) {
      off[node] = e0 + x - v;
      dis[node] = rsqrtf((float)(v + 1));
    }
  }
  __syncthreads();
  for (int k = e0 + t; k < e1; k += 256) {
    unsigned u = buf[k];
    int d = u >> 25;
    int p = atomicAdd(&cur[d], 1);
    csr[e0 + p] = (int)(u & 0x1FFFFFFu);
  }
}

// convert 3 weight matrices to f16 transposed: Wt[l][n][k] = W_l[k][n]
__global__ void wtcvt_kernel(const float* __restrict__ W0, const float* __restrict__ W1,
                             const float* __restrict__ W2, _Float16* __restrict__ Wt) {
  int i = blockIdx.x * 256 + threadIdx.x;
  if (i >= 3 * FEAT * FEAT) return;
  int l = i / (FEAT * FEAT);
  int r = i - l * (FEAT * FEAT);
  int nn = r >> 7, kk = r & 127;
  const float* W = (l == 0) ? W0 : (l == 1) ? W1 : W2;
  Wt[i] = (_Float16)W[kk * FEAT + nn];
}

// Hs(f16) = (X @ W) * dis[row] via v_mfma_f32_16x16x32_f16
template <bool F32IN>
__global__ void __launch_bounds__(256) gemm_mfma_kernel(const void* __restrict__ Xin,
                                                        const _Float16* __restrict__ Wt,
                                                        const float* __restrict__ dis,
                                                        _Float16* __restrict__ Hs, int n) {
  __shared__ _Float16 st[64 * FEAT];  // 16 KB epilogue staging
  int tid = threadIdx.x;
  int w = tid >> 6, lane = tid & 63;
  int l15 = lane & 15, hi = lane >> 4;

  int rowA = blockIdx.x * 64 + w * 16 + l15;
  int rA = min(rowA, n - 1);
  const _Float16* Xh = (const _Float16*)Xin;
  const float* Xf = (const float*)Xin;

  f4 acc[8];
#pragma unroll
  for (int nb = 0; nb < 8; ++nb) acc[nb] = (f4)(0.f);

#pragma unroll
  for (int kk = 0; kk < FEAT; kk += 32) {
    int ko = kk + hi * 8;
    h8 a;
    if (F32IN) {
      float4 x0 = *(const float4*)&Xf[(size_t)rA * FEAT + ko];
      float4 x1 = *(const float4*)&Xf[(size_t)rA * FEAT + ko + 4];
      a[0] = (_Float16)x0.x; a[1] = (_Float16)x0.y; a[2] = (_Float16)x0.z; a[3] = (_Float16)x0.w;
      a[4] = (_Float16)x1.x; a[5] = (_Float16)x1.y; a[6] = (_Float16)x1.z; a[7] = (_Float16)x1.w;
    } else {
      a = *(const h8*)&Xh[(size_t)rA * FEAT + ko];
    }
#pragma unroll
    for (int nb = 0; nb < 8; ++nb) {
      h8 bfr = *(const h8*)&Wt[(nb * 16 + l15) * FEAT + ko];
      acc[nb] = __builtin_amdgcn_mfma_f32_16x16x32_f16(a, bfr, acc[nb], 0, 0, 0);
    }
  }

  float dv[4];
#pragma unroll
  for (int r = 0; r < 4; ++r) {
    int grow = blockIdx.x * 64 + w * 16 + hi * 4 + r;
    dv[r] = dis[min(grow, n - 1)];
  }
#pragma unroll
  for (int nb = 0; nb < 8; ++nb)
#pragma unroll
    for (int r = 0; r < 4; ++r)
      st[(w * 16 + hi * 4 + r) * FEAT + nb * 16 + l15] = (_Float16)(acc[nb][r] * dv[r]);
  __syncthreads();

  int rowbase = blockIdx.x * 64;
#pragma unroll
  for (int i = tid; i < 64 * FEAT / 8; i += 256) {
    int row = rowbase + (i >> 4);
    if (row < n)
      *(uint4*)&Hs[(size_t)row * FEAT + (i & 15) * 8] =
          *(const uint4*)&st[(i >> 4) * FEAT + (i & 15) * 8];
  }
}

// out(f16) = relu(dis[i] * (Hs[i] + sum_{e: dst=i} Hs[src_e]) + b)
// one wave per node; f16 row = 256 B; gather unrolled x8 (8 loads in flight)
__global__ void __launch_bounds__(256) agg_kernel(const unsigned* __restrict__ Hs,
                                                  const int* __restrict__ csr,
                                                  const int* __restrict__ off,
                                                  const float* __restrict__ dis,
                                                  const float* __restrict__ b,
                                                  unsigned* __restrict__ out, int n) {
  int wave = threadIdx.x >> 6;
  int lane = threadIdx.x & 63;
  int node = blockIdx.x * 4 + wave;
  if (node >= n) return;
  int s = off[node];
  int e = off[node + 1];
  float2 a0 = h2f2(Hs[node * 64 + lane]);  // self-loop term
  float2 a1 = make_float2(0.f, 0.f), a2 = make_float2(0.f, 0.f), a3 = make_float2(0.f, 0.f);
  float2 a4 = make_float2(0.f, 0.f), a5 = make_float2(0.f, 0.f);
  float2 a6 = make_float2(0.f, 0.f), a7 = make_float2(0.f, 0.f);
  int k = s;
  for (; k + 8 <= e; k += 8) {
    int s0 = csr[k], s1 = csr[k + 1], s2 = csr[k + 2], s3 = csr[k + 3];
    int s4 = csr[k + 4], s5 = csr[k + 5], s6 = csr[k + 6], s7 = csr[k + 7];
    unsigned u0 = Hs[s0 * 64 + lane], u1 = Hs[s1 * 64 + lane];
    unsigned u2 = Hs[s2 * 64 + lane], u3 = Hs[s3 * 64 + lane];
    unsigned u4 = Hs[s4 * 64 + lane], u5 = Hs[s5 * 64 + lane];
    unsigned u6 = Hs[s6 * 64 + lane], u7 = Hs[s7 * 64 + lane];
    float2 v0 = h2f2(u0), v1 = h2f2(u1), v2 = h2f2(u2), v3 = h2f2(u3);
    float2 v4 = h2f2(u4), v5 = h2f2(u5), v6 = h2f2(u6), v7 = h2f2(u7);
    a0.x += v0.x; a0.y += v0.y;
    a1.x += v1.x; a1.y += v1.y;
    a2.x += v2.x; a2.y += v2.y;
    a3.x += v3.x; a3.y += v3.y;
    a4.x += v4.x; a4.y += v4.y;
    a5.x += v5.x; a5.y += v5.y;
    a6.x += v6.x; a6.y += v6.y;
    a7.x += v7.x; a7.y += v7.y;
  }
  for (; k + 4 <= e; k += 4) {
    int s0 = csr[k], s1 = csr[k + 1], s2 = csr[k + 2], s3 = csr[k + 3];
    unsigned u0 = Hs[s0 * 64 + lane], u1 = Hs[s1 * 64 + lane];
    unsigned u2 = Hs[s2 * 64 + lane], u3 = Hs[s3 * 64 + lane];
    float2 v0 = h2f2(u0), v1 = h2f2(u1), v2 = h2f2(u2), v3 = h2f2(u3);
    a0.x += v0.x; a0.y += v0.y;
    a1.x += v1.x; a1.y += v1.y;
    a2.x += v2.x; a2.y += v2.y;
    a3.x += v3.x; a3.y += v3.y;
  }
  for (; k < e; ++k) {
    float2 v = h2f2(Hs[csr[k] * 64 + lane]);
    a0.x += v.x;
    a0.y += v.y;
  }
  a0.x += a1.x + a2.x + a3.x + a4.x + a5.x + a6.x + a7.x;
  a0.y += a1.y + a2.y + a3.y + a4.y + a5.y + a6.y + a7.y;
  float d = dis[node];
  float2 bb = ((const float2*)b)[lane];
  float ox = fmaxf(fmaf(d, a0.x, bb.x), 0.f);
  float oy = fmaxf(fmaf(d, a0.y, bb.y), 0.f);
  out[node * 64 + lane] = f2h2(ox, oy);
}

// graph boundaries from sorted batch
__global__ void bounds_kernel(const int* __restrict__ batch, int* __restrict__ gstart,
                              int n, int g) {
  int i = blockIdx.x * 256 + threadIdx.x;
  if (i >= n) return;
  int bi = batch[i];
  int bp = (i == 0) ? -1 : batch[i - 1];
  for (int q = bp + 1; q <= bi; ++q) gstart[q] = i;
  if (i == n - 1) {
    for (int q = bi + 1; q <= g; ++q) gstart[q] = n;
  }
}

// mean-pool per graph (f16 input) + linear(128->10) + log_softmax
__global__ void __launch_bounds__(128) pool_kernel(const __half* __restrict__ h,
                                                   const int* __restrict__ gstart,
                                                   const float* __restrict__ lw,
                                                   const float* __restrict__ lb,
                                                   float* __restrict__ out) {
  int g = blockIdx.x;
  int t = threadIdx.x;
  int s = gstart[g];
  int e = gstart[g + 1];
  float a0 = 0.f, a1 = 0.f, a2 = 0.f, a3 = 0.f;
  int i = s;
  for (; i + 4 <= e; i += 4) {
    a0 += __half2float(h[(size_t)i * FEAT + t]);
    a1 += __half2float(h[(size_t)(i + 1) * FEAT + t]);
    a2 += __half2float(h[(size_t)(i + 2) * FEAT + t]);
    a3 += __half2float(h[(size_t)(i + 3) * FEAT + t]);
  }
  for (; i < e; ++i) a0 += __half2float(h[(size_t)i * FEAT + t]);
  float acc = a0 + a1 + a2 + a3;
  float cnt = (float)(e - s);
  float pooled = acc / fmaxf(cnt, 1.f);
  __shared__ float lds[FEAT];
  __shared__ float logits[NCLASS];
  lds[t] = pooled;
  __syncthreads();
  if (t < NCLASS) {
    float z = lb[t];
    for (int k = 0; k < FEAT; ++k) z += lds[k] * lw[k * NCLASS + t];
    logits[t] = z;
  }
  __syncthreads();
  if (t < NCLASS) {
    float m = logits[0];
#pragma unroll
    for (int c = 1; c < NCLASS; ++c) m = fmaxf(m, logits[c]);
    float ssum = 0.f;
#pragma unroll
    for (int c = 0; c < NCLASS; ++c) ssum += expf(logits[c] - m);
    out[(size_t)g * NCLASS + t] = logits[t] - m - logf(ssum);
  }
}

extern "C" void kernel_launch(void* const* d_in, const int* in_sizes, int n_in,
                              void* d_out, int out_size, void* d_ws, size_t ws_size,
                              hipStream_t stream) {
  const float* x = (const float*)d_in[0];
  const int* ei = (const int*)d_in[1];
  const int* batch = (const int*)d_in[2];
  const float* W0 = (const float*)d_in[3];
  const float* b0 = (const float*)d_in[4];
  const float* W1 = (const float*)d_in[5];
  const float* b1 = (const float*)d_in[6];
  const float* W2 = (const float*)d_in[7];
  const float* b2 = (const float*)d_in[8];
  const float* lw = (const float*)d_in[9];
  const float* lb = (const float*)d_in[10];

  int n = in_sizes[2];        // 50000 nodes
  int ne = in_sizes[1] / 2;   // 800000 edges
  int g = out_size / NCLASS;  // 512 graphs
  int nb = (n + 127) >> 7;    // dst buckets (391)
  int hblocks = 120;
  int epb = (ne + hblocks - 1) / hblocks;

  char* ws = (char*)d_ws;
  size_t p = 0;
  auto alloc = [&](size_t bytes) {
    size_t cur = p;
    p += (bytes + 255) & ~(size_t)255;
    return cur;
  };
  int* off = (int*)(ws + alloc((size_t)(n + 1) * 4));
  int* csr = (int*)(ws + alloc((size_t)ne * 4));
  int* bhist = (int*)(ws + alloc((size_t)NB_MAX * 4));
  int* bstart = (int*)(ws + alloc((size_t)(NB_MAX + 1) * 4));
  int* bcur = (int*)(ws + alloc((size_t)NB_MAX * 4));
  int* gstart = (int*)(ws + alloc((size_t)(g + 1) * 4));
  float* dis = (float*)(ws + alloc((size_t)n * 4));
  unsigned* buf = (unsigned*)(ws + alloc((size_t)ne * 4));
  _Float16* Wt = (_Float16*)(ws + alloc((size_t)3 * FEAT * FEAT * 2));
  _Float16* Hs = (_Float16*)(ws + alloc((size_t)n * FEAT * 2));
  _Float16* Hb = (_Float16*)(ws + alloc((size_t)n * FEAT * 2));

  hipMemsetAsync(bhist, 0, NB_MAX * 4, stream);

  hist_kernel<<<hblocks, 256, 0, stream>>>(ei, bhist, ne, nb, epb);
  bscan_kernel<<<1, 512, 0, stream>>>(bhist, bstart, bcur, off, nb, n, ne);
  scatter_kernel<<<hblocks, 256, 0, stream>>>(ei, bcur, buf, ne, nb, epb);
  bucket_build_kernel<<<nb, 256, 0, stream>>>(buf, bstart, off, csr, dis, n);
  wtcvt_kernel<<<(3 * FEAT * FEAT + 255) / 256, 256, 0, stream>>>(W0, W1, W2, Wt);

  const float* bv[3] = {b0, b1, b2};
  for (int l = 0; l < 3; ++l) {
    const void* in = (l == 0) ? (const void*)x : (const void*)Hb;
    const _Float16* wt = Wt + (size_t)l * FEAT * FEAT;
    if (l == 0)
      gemm_mfma_kernel<true><<<(n + 63) / 64, 256, 0, stream>>>(in, wt, dis, Hs, n);
    else
      gemm_mfma_kernel<false><<<(n + 63) / 64, 256, 0, stream>>>(in, wt, dis, Hs, n);
    agg_kernel<<<(n + 3) / 4, 256, 0, stream>>>((const unsigned*)Hs, csr, off, dis, bv[l],
                                                (unsigned*)Hb, n);
  }

  bounds_kernel<<<(n + 255) / 256, 256, 0, stream>>>(batch, gstart, n, g);
  pool_kernel<<<g, 128, 0, stream>>>((const __half*)Hb, gstart, lw, lb, (float*)d_out);
}

// Round 6
// 222.508 us; speedup vs baseline: 2.9548x; 1.0514x over previous
//
#include <hip/hip_runtime.h>
#include <hip/hip_fp16.h>

// GCN forward: 3x (MFMA GEMM + normalized adjacency aggregate + ReLU) + mean-pool + linear + log_softmax
// N=50000, E=800000, F=H=128, C=10, G=512
// Round 6: agg restructured — 4x16-lane groups, each gathers a full 256B f16 row
// (16B/lane), 16 edges in flight per wave, shfl-xor butterfly merge. wtcvt merged
// into hist launch.

#define FEAT 128
#define NCLASS 10
#define NB_MAX 512  // max dst buckets (n <= 65536 here: 391)

typedef _Float16 h8 __attribute__((ext_vector_type(8)));
typedef float f4 __attribute__((ext_vector_type(4)));

// ---- pass 0: bucket histogram of dst>>7 (blocks 0..hb-1) + Wt convert (rest) ----
__global__ void __launch_bounds__(256) hist_wt_kernel(const int* __restrict__ ei,
                                                      int* __restrict__ bhist,
                                                      int ne, int nb, int epb, int hb,
                                                      const float* __restrict__ W0,
                                                      const float* __restrict__ W1,
                                                      const float* __restrict__ W2,
                                                      _Float16* __restrict__ Wt) {
  int t = threadIdx.x;
  if (blockIdx.x >= hb) {
    // Wt[l][n][k] = W_l[k][n]
    int i = (blockIdx.x - hb) * 256 + t;
    if (i < 3 * FEAT * FEAT) {
      int l = i / (FEAT * FEAT);
      int r = i - l * (FEAT * FEAT);
      int nn = r >> 7, kk = r & 127;
      const float* W = (l == 0) ? W0 : (l == 1) ? W1 : W2;
      Wt[i] = (_Float16)W[kk * FEAT + nn];
    }
    return;
  }
  __shared__ int lh[NB_MAX];
  for (int i = t; i < nb; i += 256) lh[i] = 0;
  __syncthreads();
  int r0 = blockIdx.x * epb;
  int r1 = min(r0 + epb, ne);
  for (int k = r0 + t; k < r1; k += 256) atomicAdd(&lh[ei[ne + k] >> 7], 1);
  __syncthreads();
  for (int i = t; i < nb; i += 256)
    if (lh[i]) atomicAdd(&bhist[i], lh[i]);
}

// ---- exclusive scan of bucket counts -> bstart (kept) and bcur (consumed) ----
__global__ void __launch_bounds__(512) bscan_kernel(const int* __restrict__ bhist,
                                                    int* __restrict__ bstart,
                                                    int* __restrict__ bcur,
                                                    int* __restrict__ off,
                                                    int nb, int n, int ne) {
  __shared__ int sh[512];
  int t = threadIdx.x;
  int v = (t < nb) ? bhist[t] : 0;
  sh[t] = v;
  __syncthreads();
  int x = v;
  for (int d = 1; d < 512; d <<= 1) {
    int y = (t >= d) ? sh[t - d] : 0;
    __syncthreads();
    x += y;
    sh[t] = x;
    __syncthreads();
  }
  if (t < nb) {
    bstart[t] = x - v;
    bcur[t] = x - v;
  }
  if (t == 0) {
    bstart[nb] = ne;
    off[n] = ne;
  }
}

// ---- pass 1: scatter packed (dst&127,src) into dst-buckets ----
__global__ void __launch_bounds__(256) scatter_kernel(const int* __restrict__ ei,
                                                      int* __restrict__ bcur,
                                                      unsigned* __restrict__ buf,
                                                      int ne, int nb, int epb) {
  __shared__ int lh[NB_MAX], lbs[NB_MAX];
  int t = threadIdx.x;
  for (int i = t; i < nb; i += 256) lh[i] = 0;
  __syncthreads();
  int r0 = blockIdx.x * epb;
  int r1 = min(r0 + epb, ne);
  for (int k = r0 + t; k < r1; k += 256) atomicAdd(&lh[ei[ne + k] >> 7], 1);
  __syncthreads();
  for (int i = t; i < nb; i += 256) {
    int c = lh[i];
    lbs[i] = c ? atomicAdd(&bcur[i], c) : 0;
    lh[i] = 0;  // reuse as local cursor
  }
  __syncthreads();
  for (int k = r0 + t; k < r1; k += 256) {
    int src = ei[k];
    int dst = ei[ne + k];
    int b = dst >> 7;
    int p = lbs[b] + atomicAdd(&lh[b], 1);
    buf[p] = (unsigned)src | ((unsigned)(dst & 127) << 25);
  }
}

// ---- pass 2: one block per bucket: LDS count -> scan -> dis/off/csr ----
__global__ void __launch_bounds__(256) bucket_build_kernel(const unsigned* __restrict__ buf,
                                                           const int* __restrict__ bstart,
                                                           int* __restrict__ off,
                                                           int* __restrict__ csr,
                                                           float* __restrict__ dis, int n) {
  __shared__ int cnt[128], cur[128], sh[128];
  int b = blockIdx.x, t = threadIdx.x;
  int e0 = bstart[b], e1 = bstart[b + 1];
  if (t < 128) cnt[t] = 0;
  __syncthreads();
  for (int k = e0 + t; k < e1; k += 256) atomicAdd(&cnt[buf[k] >> 25], 1);
  __syncthreads();
  int v = (t < 128) ? cnt[t] : 0;
  if (t < 128) sh[t] = v;
  __syncthreads();
  int x = v;
  for (int d = 1; d < 128; d <<= 1) {
    int y = (t < 128 && t >= d) ? sh[t - d] : 0;
    __syncthreads();
    if (t < 128) {
      x += y;
      sh[t] = x;
    }
    __syncthreads();
  }
  if (t < 128) {
    int node = (b << 7) + t;
    cur[t] = x - v;
    if (node < n) {
      off[node] = e0 + x - v;
      dis[node] = rsqrtf((float)(v + 1));
    }
  }
  __syncthreads();
  for (int k = e0 + t; k < e1; k += 256) {
    unsigned u = buf[k];
    int d = u >> 25;
    int p = atomicAdd(&cur[d], 1);
    csr[e0 + p] = (int)(u & 0x1FFFFFFu);
  }
}

// Hs(f16) = (X @ W) * dis[row] via v_mfma_f32_16x16x32_f16
template <bool F32IN>
__global__ void __launch_bounds__(256) gemm_mfma_kernel(const void* __restrict__ Xin,
                                                        const _Float16* __restrict__ Wt,
                                                        const float* __restrict__ dis,
                                                        _Float16* __restrict__ Hs, int n) {
  __shared__ _Float16 st[64 * FEAT];  // 16 KB epilogue staging
  int tid = threadIdx.x;
  int w = tid >> 6, lane = tid & 63;
  int l15 = lane & 15, hi = lane >> 4;

  int rowA = blockIdx.x * 64 + w * 16 + l15;
  int rA = min(rowA, n - 1);
  const _Float16* Xh = (const _Float16*)Xin;
  const float* Xf = (const float*)Xin;

  f4 acc[8];
#pragma unroll
  for (int nb = 0; nb < 8; ++nb) acc[nb] = (f4)(0.f);

#pragma unroll
  for (int kk = 0; kk < FEAT; kk += 32) {
    int ko = kk + hi * 8;
    h8 a;
    if (F32IN) {
      float4 x0 = *(const float4*)&Xf[(size_t)rA * FEAT + ko];
      float4 x1 = *(const float4*)&Xf[(size_t)rA * FEAT + ko + 4];
      a[0] = (_Float16)x0.x; a[1] = (_Float16)x0.y; a[2] = (_Float16)x0.z; a[3] = (_Float16)x0.w;
      a[4] = (_Float16)x1.x; a[5] = (_Float16)x1.y; a[6] = (_Float16)x1.z; a[7] = (_Float16)x1.w;
    } else {
      a = *(const h8*)&Xh[(size_t)rA * FEAT + ko];
    }
#pragma unroll
    for (int nb = 0; nb < 8; ++nb) {
      h8 bfr = *(const h8*)&Wt[(nb * 16 + l15) * FEAT + ko];
      acc[nb] = __builtin_amdgcn_mfma_f32_16x16x32_f16(a, bfr, acc[nb], 0, 0, 0);
    }
  }

  float dv[4];
#pragma unroll
  for (int r = 0; r < 4; ++r) {
    int grow = blockIdx.x * 64 + w * 16 + hi * 4 + r;
    dv[r] = dis[min(grow, n - 1)];
  }
#pragma unroll
  for (int nb = 0; nb < 8; ++nb)
#pragma unroll
    for (int r = 0; r < 4; ++r)
      st[(w * 16 + hi * 4 + r) * FEAT + nb * 16 + l15] = (_Float16)(acc[nb][r] * dv[r]);
  __syncthreads();

  int rowbase = blockIdx.x * 64;
#pragma unroll
  for (int i = tid; i < 64 * FEAT / 8; i += 256) {
    int row = rowbase + (i >> 4);
    if (row < n)
      *(uint4*)&Hs[(size_t)row * FEAT + (i & 15) * 8] =
          *(const uint4*)&st[(i >> 4) * FEAT + (i & 15) * 8];
  }
}

// out(f16) = relu(dis[i] * (Hs[i] + sum_{e: dst=i} Hs[src_e]) + b)
// one wave per node, split into 4x16-lane groups; each group gathers a FULL
// 256B row (h8 = 16B/lane) -> 4 rows per gather instr, 16 edges in flight.
// Tail lanes clamp src to row 0 (L1-hot) and predicate the accumulate.
// shfl-xor butterfly (16,32) merges group partials; group 0 writes the row.
__global__ void __launch_bounds__(256) agg_kernel(const h8* __restrict__ Hs,
                                                  const int* __restrict__ csr,
                                                  const int* __restrict__ off,
                                                  const float* __restrict__ dis,
                                                  const float* __restrict__ b,
                                                  h8* __restrict__ out, int n) {
  int wave = threadIdx.x >> 6;
  int lane = threadIdx.x & 63;
  int grp = lane >> 4, lig = lane & 15;
  int node = blockIdx.x * 4 + wave;
  if (node >= n) return;
  int s = off[node];
  int e = off[node + 1];

  float acc[8];
  if (grp == 0) {
    h8 v = Hs[(size_t)node * 16 + lig];  // self-loop term
#pragma unroll
    for (int j = 0; j < 8; ++j) acc[j] = (float)v[j];
  } else {
#pragma unroll
    for (int j = 0; j < 8; ++j) acc[j] = 0.f;
  }

  for (int k = s; k < e; k += 16) {
    int k0 = k + grp, k1 = k0 + 4, k2 = k0 + 8, k3 = k0 + 12;
    int i0 = (k0 < e) ? csr[k0] : -1;
    int i1 = (k1 < e) ? csr[k1] : -1;
    int i2 = (k2 < e) ? csr[k2] : -1;
    int i3 = (k3 < e) ? csr[k3] : -1;
    h8 v0 = Hs[(size_t)max(i0, 0) * 16 + lig];
    h8 v1 = Hs[(size_t)max(i1, 0) * 16 + lig];
    h8 v2 = Hs[(size_t)max(i2, 0) * 16 + lig];
    h8 v3 = Hs[(size_t)max(i3, 0) * 16 + lig];
    if (i0 >= 0) {
#pragma unroll
      for (int j = 0; j < 8; ++j) acc[j] += (float)v0[j];
    }
    if (i1 >= 0) {
#pragma unroll
      for (int j = 0; j < 8; ++j) acc[j] += (float)v1[j];
    }
    if (i2 >= 0) {
#pragma unroll
      for (int j = 0; j < 8; ++j) acc[j] += (float)v2[j];
    }
    if (i3 >= 0) {
#pragma unroll
      for (int j = 0; j < 8; ++j) acc[j] += (float)v3[j];
    }
  }

  // merge the 4 groups' partials (butterfly over lane bits 4,5)
#pragma unroll
  for (int j = 0; j < 8; ++j) {
    acc[j] += __shfl_xor(acc[j], 16);
    acc[j] += __shfl_xor(acc[j], 32);
  }

  if (grp == 0) {
    float d = dis[node];
    float4 b0 = ((const float4*)b)[lig * 2];
    float4 b1 = ((const float4*)b)[lig * 2 + 1];
    h8 o;
    o[0] = (_Float16)fmaxf(fmaf(d, acc[0], b0.x), 0.f);
    o[1] = (_Float16)fmaxf(fmaf(d, acc[1], b0.y), 0.f);
    o[2] = (_Float16)fmaxf(fmaf(d, acc[2], b0.z), 0.f);
    o[3] = (_Float16)fmaxf(fmaf(d, acc[3], b0.w), 0.f);
    o[4] = (_Float16)fmaxf(fmaf(d, acc[4], b1.x), 0.f);
    o[5] = (_Float16)fmaxf(fmaf(d, acc[5], b1.y), 0.f);
    o[6] = (_Float16)fmaxf(fmaf(d, acc[6], b1.z), 0.f);
    o[7] = (_Float16)fmaxf(fmaf(d, acc[7], b1.w), 0.f);
    out[(size_t)node * 16 + lig] = o;
  }
}

// graph boundaries from sorted batch
__global__ void bounds_kernel(const int* __restrict__ batch, int* __restrict__ gstart,
                              int n, int g) {
  int i = blockIdx.x * 256 + threadIdx.x;
  if (i >= n) return;
  int bi = batch[i];
  int bp = (i == 0) ? -1 : batch[i - 1];
  for (int q = bp + 1; q <= bi; ++q) gstart[q] = i;
  if (i == n - 1) {
    for (int q = bi + 1; q <= g; ++q) gstart[q] = n;
  }
}

// mean-pool per graph (f16 input) + linear(128->10) + log_softmax
__global__ void __launch_bounds__(128) pool_kernel(const __half* __restrict__ h,
                                                   const int* __restrict__ gstart,
                                                   const float* __restrict__ lw,
                                                   const float* __restrict__ lb,
                                                   float* __restrict__ out) {
  int g = blockIdx.x;
  int t = threadIdx.x;
  int s = gstart[g];
  int e = gstart[g + 1];
  float a0 = 0.f, a1 = 0.f, a2 = 0.f, a3 = 0.f;
  int i = s;
  for (; i + 4 <= e; i += 4) {
    a0 += __half2float(h[(size_t)i * FEAT + t]);
    a1 += __half2float(h[(size_t)(i + 1) * FEAT + t]);
    a2 += __half2float(h[(size_t)(i + 2) * FEAT + t]);
    a3 += __half2float(h[(size_t)(i + 3) * FEAT + t]);
  }
  for (; i < e; ++i) a0 += __half2float(h[(size_t)i * FEAT + t]);
  float acc = a0 + a1 + a2 + a3;
  float cnt = (float)(e - s);
  float pooled = acc / fmaxf(cnt, 1.f);
  __shared__ float lds[FEAT];
  __shared__ float logits[NCLASS];
  lds[t] = pooled;
  __syncthreads();
  if (t < NCLASS) {
    float z = lb[t];
    for (int k = 0; k < FEAT; ++k) z += lds[k] * lw[k * NCLASS + t];
    logits[t] = z;
  }
  __syncthreads();
  if (t < NCLASS) {
    float m = logits[0];
#pragma unroll
    for (int c = 1; c < NCLASS; ++c) m = fmaxf(m, logits[c]);
    float ssum = 0.f;
#pragma unroll
    for (int c = 0; c < NCLASS; ++c) ssum += expf(logits[c] - m);
    out[(size_t)g * NCLASS + t] = logits[t] - m - logf(ssum);
  }
}

extern "C" void kernel_launch(void* const* d_in, const int* in_sizes, int n_in,
                              void* d_out, int out_size, void* d_ws, size_t ws_size,
                              hipStream_t stream) {
  const float* x = (const float*)d_in[0];
  const int* ei = (const int*)d_in[1];
  const int* batch = (const int*)d_in[2];
  const float* W0 = (const float*)d_in[3];
  const float* b0 = (const float*)d_in[4];
  const float* W1 = (const float*)d_in[5];
  const float* b1 = (const float*)d_in[6];
  const float* W2 = (const float*)d_in[7];
  const float* b2 = (const float*)d_in[8];
  const float* lw = (const float*)d_in[9];
  const float* lb = (const float*)d_in[10];

  int n = in_sizes[2];        // 50000 nodes
  int ne = in_sizes[1] / 2;   // 800000 edges
  int g = out_size / NCLASS;  // 512 graphs
  int nb = (n + 127) >> 7;    // dst buckets (391)
  int hblocks = 120;
  int epb = (ne + hblocks - 1) / hblocks;
  int wtblocks = (3 * FEAT * FEAT + 255) / 256;  // 192

  char* ws = (char*)d_ws;
  size_t p = 0;
  auto alloc = [&](size_t bytes) {
    size_t cur = p;
    p += (bytes + 255) & ~(size_t)255;
    return cur;
  };
  int* off = (int*)(ws + alloc((size_t)(n + 1) * 4));
  int* csr = (int*)(ws + alloc((size_t)ne * 4));
  int* bhist = (int*)(ws + alloc((size_t)NB_MAX * 4));
  int* bstart = (int*)(ws + alloc((size_t)(NB_MAX + 1) * 4));
  int* bcur = (int*)(ws + alloc((size_t)NB_MAX * 4));
  int* gstart = (int*)(ws + alloc((size_t)(g + 1) * 4));
  float* dis = (float*)(ws + alloc((size_t)n * 4));
  unsigned* buf = (unsigned*)(ws + alloc((size_t)ne * 4));
  _Float16* Wt = (_Float16*)(ws + alloc((size_t)3 * FEAT * FEAT * 2));
  _Float16* Hs = (_Float16*)(ws + alloc((size_t)n * FEAT * 2));
  _Float16* Hb = (_Float16*)(ws + alloc((size_t)n * FEAT * 2));

  hipMemsetAsync(bhist, 0, NB_MAX * 4, stream);

  hist_wt_kernel<<<hblocks + wtblocks, 256, 0, stream>>>(ei, bhist, ne, nb, epb, hblocks,
                                                         W0, W1, W2, Wt);
  bscan_kernel<<<1, 512, 0, stream>>>(bhist, bstart, bcur, off, nb, n, ne);
  scatter_kernel<<<hblocks, 256, 0, stream>>>(ei, bcur, buf, ne, nb, epb);
  bucket_build_kernel<<<nb, 256, 0, stream>>>(buf, bstart, off, csr, dis, n);

  const float* bv[3] = {b0, b1, b2};
  for (int l = 0; l < 3; ++l) {
    const void* in = (l == 0) ? (const void*)x : (const void*)Hb;
    const _Float16* wt = Wt + (size_t)l * FEAT * FEAT;
    if (l == 0)
      gemm_mfma_kernel<true><<<(n + 63) / 64, 256, 0, stream>>>(in, wt, dis, Hs, n);
    else
      gemm_mfma_kernel<false><<<(n + 63) / 64, 256, 0, stream>>>(in, wt, dis, Hs, n);
    agg_kernel<<<(n + 3) / 4, 256, 0, stream>>>((const h8*)Hs, csr, off, dis, bv[l],
                                                (h8*)Hb, n);
  }

  bounds_kernel<<<(n + 255) / 256, 256, 0, stream>>>(batch, gstart, n, g);
  pool_kernel<<<g, 128, 0, stream>>>((const __half*)Hb, gstart, lw, lb, (float*)d_out);
}

// Round 7
// 209.391 us; speedup vs baseline: 3.1399x; 1.0626x over previous
//
#include <hip/hip_runtime.h>
#include <hip/hip_fp16.h>

// GCN forward: 3x (MFMA GEMM + normalized adjacency aggregate + ReLU) + mean-pool + linear + log_softmax
// N=50000, E=800000, F=H=128, C=10, G=512
// Round 7: fused agg+gemm for layers 1,2 — per-block: gather/aggregate 64 node
// rows into a swizzled LDS A-tile (16-lane group per node, no shfl), then MFMA
// with next layer's W. Kills the Hb round-trip (51 MB) + 2 launches and fixes
// agg load imbalance (block = 64 consecutive nodes).

#define FEAT 128
#define NCLASS 10
#define NB_MAX 512  // max dst buckets (n <= 65536 here: 391)

typedef _Float16 h8 __attribute__((ext_vector_type(8)));
typedef float f4 __attribute__((ext_vector_type(4)));

// LDS tile swizzle: row stride 256B; XOR row&7 into byte bits 4..6 so that
// phase-2 column reads (16 rows @ same col) spread across 8 16B slots (2-way = free).
__device__ inline int swz(int row, int cbyte) { return row * 256 + (cbyte ^ ((row & 7) << 4)); }

// ---- pass 0: bucket histogram of dst>>7 (blocks 0..hb-1) + Wt convert (rest) ----
__global__ void __launch_bounds__(256) hist_wt_kernel(const int* __restrict__ ei,
                                                      int* __restrict__ bhist,
                                                      int ne, int nb, int epb, int hb,
                                                      const float* __restrict__ W0,
                                                      const float* __restrict__ W1,
                                                      const float* __restrict__ W2,
                                                      _Float16* __restrict__ Wt) {
  int t = threadIdx.x;
  if (blockIdx.x >= hb) {
    // Wt[l][n][k] = W_l[k][n]
    int i = (blockIdx.x - hb) * 256 + t;
    if (i < 3 * FEAT * FEAT) {
      int l = i / (FEAT * FEAT);
      int r = i - l * (FEAT * FEAT);
      int nn = r >> 7, kk = r & 127;
      const float* W = (l == 0) ? W0 : (l == 1) ? W1 : W2;
      Wt[i] = (_Float16)W[kk * FEAT + nn];
    }
    return;
  }
  __shared__ int lh[NB_MAX];
  for (int i = t; i < nb; i += 256) lh[i] = 0;
  __syncthreads();
  int r0 = blockIdx.x * epb;
  int r1 = min(r0 + epb, ne);
  for (int k = r0 + t; k < r1; k += 256) atomicAdd(&lh[ei[ne + k] >> 7], 1);
  __syncthreads();
  for (int i = t; i < nb; i += 256)
    if (lh[i]) atomicAdd(&bhist[i], lh[i]);
}

// ---- exclusive scan of bucket counts -> bstart (kept) and bcur (consumed) ----
__global__ void __launch_bounds__(512) bscan_kernel(const int* __restrict__ bhist,
                                                    int* __restrict__ bstart,
                                                    int* __restrict__ bcur,
                                                    int* __restrict__ off,
                                                    int nb, int n, int ne) {
  __shared__ int sh[512];
  int t = threadIdx.x;
  int v = (t < nb) ? bhist[t] : 0;
  sh[t] = v;
  __syncthreads();
  int x = v;
  for (int d = 1; d < 512; d <<= 1) {
    int y = (t >= d) ? sh[t - d] : 0;
    __syncthreads();
    x += y;
    sh[t] = x;
    __syncthreads();
  }
  if (t < nb) {
    bstart[t] = x - v;
    bcur[t] = x - v;
  }
  if (t == 0) {
    bstart[nb] = ne;
    off[n] = ne;
  }
}

// ---- pass 1: scatter packed (dst&127,src) into dst-buckets ----
__global__ void __launch_bounds__(256) scatter_kernel(const int* __restrict__ ei,
                                                      int* __restrict__ bcur,
                                                      unsigned* __restrict__ buf,
                                                      int ne, int nb, int epb) {
  __shared__ int lh[NB_MAX], lbs[NB_MAX];
  int t = threadIdx.x;
  for (int i = t; i < nb; i += 256) lh[i] = 0;
  __syncthreads();
  int r0 = blockIdx.x * epb;
  int r1 = min(r0 + epb, ne);
  for (int k = r0 + t; k < r1; k += 256) atomicAdd(&lh[ei[ne + k] >> 7], 1);
  __syncthreads();
  for (int i = t; i < nb; i += 256) {
    int c = lh[i];
    lbs[i] = c ? atomicAdd(&bcur[i], c) : 0;
    lh[i] = 0;  // reuse as local cursor
  }
  __syncthreads();
  for (int k = r0 + t; k < r1; k += 256) {
    int src = ei[k];
    int dst = ei[ne + k];
    int b = dst >> 7;
    int p = lbs[b] + atomicAdd(&lh[b], 1);
    buf[p] = (unsigned)src | ((unsigned)(dst & 127) << 25);
  }
}

// ---- pass 2: one block per bucket: LDS count -> scan -> dis/off/csr ----
__global__ void __launch_bounds__(256) bucket_build_kernel(const unsigned* __restrict__ buf,
                                                           const int* __restrict__ bstart,
                                                           int* __restrict__ off,
                                                           int* __restrict__ csr,
                                                           float* __restrict__ dis, int n) {
  __shared__ int cnt[128], cur[128], sh[128];
  int b = blockIdx.x, t = threadIdx.x;
  int e0 = bstart[b], e1 = bstart[b + 1];
  if (t < 128) cnt[t] = 0;
  __syncthreads();
  for (int k = e0 + t; k < e1; k += 256) atomicAdd(&cnt[buf[k] >> 25], 1);
  __syncthreads();
  int v = (t < 128) ? cnt[t] : 0;
  if (t < 128) sh[t] = v;
  __syncthreads();
  int x = v;
  for (int d = 1; d < 128; d <<= 1) {
    int y = (t < 128 && t >= d) ? sh[t - d] : 0;
    __syncthreads();
    if (t < 128) {
      x += y;
      sh[t] = x;
    }
    __syncthreads();
  }
  if (t < 128) {
    int node = (b << 7) + t;
    cur[t] = x - v;
    if (node < n) {
      off[node] = e0 + x - v;
      dis[node] = rsqrtf((float)(v + 1));
    }
  }
  __syncthreads();
  for (int k = e0 + t; k < e1; k += 256) {
    unsigned u = buf[k];
    int d = u >> 25;
    int p = atomicAdd(&cur[d], 1);
    csr[e0 + p] = (int)(u & 0x1FFFFFFu);
  }
}

// Hs(f16) = (X @ W) * dis[row] via v_mfma_f32_16x16x32_f16 (layer 0, f32 input)
template <bool F32IN>
__global__ void __launch_bounds__(256) gemm_mfma_kernel(const void* __restrict__ Xin,
                                                        const _Float16* __restrict__ Wt,
                                                        const float* __restrict__ dis,
                                                        _Float16* __restrict__ Hs, int n) {
  __shared__ _Float16 st[64 * FEAT];  // 16 KB epilogue staging
  int tid = threadIdx.x;
  int w = tid >> 6, lane = tid & 63;
  int l15 = lane & 15, hi = lane >> 4;

  int rowA = blockIdx.x * 64 + w * 16 + l15;
  int rA = min(rowA, n - 1);
  const _Float16* Xh = (const _Float16*)Xin;
  const float* Xf = (const float*)Xin;

  f4 acc[8];
#pragma unroll
  for (int nb = 0; nb < 8; ++nb) acc[nb] = (f4)(0.f);

#pragma unroll
  for (int kk = 0; kk < FEAT; kk += 32) {
    int ko = kk + hi * 8;
    h8 a;
    if (F32IN) {
      float4 x0 = *(const float4*)&Xf[(size_t)rA * FEAT + ko];
      float4 x1 = *(const float4*)&Xf[(size_t)rA * FEAT + ko + 4];
      a[0] = (_Float16)x0.x; a[1] = (_Float16)x0.y; a[2] = (_Float16)x0.z; a[3] = (_Float16)x0.w;
      a[4] = (_Float16)x1.x; a[5] = (_Float16)x1.y; a[6] = (_Float16)x1.z; a[7] = (_Float16)x1.w;
    } else {
      a = *(const h8*)&Xh[(size_t)rA * FEAT + ko];
    }
#pragma unroll
    for (int nb = 0; nb < 8; ++nb) {
      h8 bfr = *(const h8*)&Wt[(nb * 16 + l15) * FEAT + ko];
      acc[nb] = __builtin_amdgcn_mfma_f32_16x16x32_f16(a, bfr, acc[nb], 0, 0, 0);
    }
  }

  float dv[4];
#pragma unroll
  for (int r = 0; r < 4; ++r) {
    int grow = blockIdx.x * 64 + w * 16 + hi * 4 + r;
    dv[r] = dis[min(grow, n - 1)];
  }
#pragma unroll
  for (int nb = 0; nb < 8; ++nb)
#pragma unroll
    for (int r = 0; r < 4; ++r)
      st[(w * 16 + hi * 4 + r) * FEAT + nb * 16 + l15] = (_Float16)(acc[nb][r] * dv[r]);
  __syncthreads();

  int rowbase = blockIdx.x * 64;
#pragma unroll
  for (int i = tid; i < 64 * FEAT / 8; i += 256) {
    int row = rowbase + (i >> 4);
    if (row < n)
      *(uint4*)&Hs[(size_t)row * FEAT + (i & 15) * 8] =
          *(const uint4*)&st[(i >> 4) * FEAT + (i & 15) * 8];
  }
}

// Fused: A = relu(dis*agg(Hs_in) + b_prev) per node (64 nodes -> swizzled LDS
// tile), then Hs_out = (A @ W) * dis via MFMA.
// Phase 1: 16-lane group per node (full 256B row = h8/lane), 4 edges in flight.
__global__ void __launch_bounds__(256) fused_kernel(const h8* __restrict__ Hs_in,
                                                    const int* __restrict__ csr,
                                                    const int* __restrict__ off,
                                                    const float* __restrict__ dis,
                                                    const float* __restrict__ bias,
                                                    const _Float16* __restrict__ Wt,
                                                    _Float16* __restrict__ Hs_out, int n) {
  __shared__ char xsb[64 * 256];  // 16 KB: A-tile, then reused as epilogue staging
  int tid = threadIdx.x;
  int w = tid >> 6, lane = tid & 63;
  int grp = lane >> 4, lig = lane & 15;
  int row0 = blockIdx.x * 64;
  int g16 = w * 4 + grp;  // 0..15: group id in block

  float4 b0 = ((const float4*)bias)[lig * 2];
  float4 b1 = ((const float4*)bias)[lig * 2 + 1];
  float bb[8] = {b0.x, b0.y, b0.z, b0.w, b1.x, b1.y, b1.z, b1.w};

  // ---- phase 1: aggregate 4 nodes per 16-lane group ----
  for (int m = 0; m < 4; ++m) {
    int ar = g16 * 4 + m;
    int nd = min(row0 + ar, n - 1);
    int s = off[nd], e = off[nd + 1];
    float a0[8], a1[8], a2[8], a3[8];
    h8 v = Hs_in[(size_t)nd * 16 + lig];  // self-loop term
#pragma unroll
    for (int j = 0; j < 8; ++j) {
      a0[j] = (float)v[j];
      a1[j] = a2[j] = a3[j] = 0.f;
    }
    for (int k = s; k < e; k += 4) {
      int i0 = csr[k];
      int i1 = (k + 1 < e) ? csr[k + 1] : -1;
      int i2 = (k + 2 < e) ? csr[k + 2] : -1;
      int i3 = (k + 3 < e) ? csr[k + 3] : -1;
      h8 v0 = Hs_in[(size_t)i0 * 16 + lig];
      h8 v1 = Hs_in[(size_t)max(i1, 0) * 16 + lig];
      h8 v2 = Hs_in[(size_t)max(i2, 0) * 16 + lig];
      h8 v3 = Hs_in[(size_t)max(i3, 0) * 16 + lig];
#pragma unroll
      for (int j = 0; j < 8; ++j) a0[j] += (float)v0[j];
      if (i1 >= 0) {
#pragma unroll
        for (int j = 0; j < 8; ++j) a1[j] += (float)v1[j];
      }
      if (i2 >= 0) {
#pragma unroll
        for (int j = 0; j < 8; ++j) a2[j] += (float)v2[j];
      }
      if (i3 >= 0) {
#pragma unroll
        for (int j = 0; j < 8; ++j) a3[j] += (float)v3[j];
      }
    }
    float d = dis[nd];
    h8 o;
#pragma unroll
    for (int j = 0; j < 8; ++j) {
      float sum = a0[j] + a1[j] + a2[j] + a3[j];
      o[j] = (_Float16)fmaxf(fmaf(d, sum, bb[j]), 0.f);
    }
    *(h8*)(xsb + swz(ar, lig * 16)) = o;
  }
  __syncthreads();

  // ---- phase 2: MFMA from LDS A-tile ----
  int l15 = lane & 15, hi = lane >> 4;
  f4 acc[8];
#pragma unroll
  for (int nb = 0; nb < 8; ++nb) acc[nb] = (f4)(0.f);
#pragma unroll
  for (int kk = 0; kk < FEAT; kk += 32) {
    int ko = kk + hi * 8;
    h8 a = *(const h8*)(xsb + swz(w * 16 + l15, ko * 2));
#pragma unroll
    for (int nb = 0; nb < 8; ++nb) {
      h8 bfr = *(const h8*)&Wt[(nb * 16 + l15) * FEAT + ko];
      acc[nb] = __builtin_amdgcn_mfma_f32_16x16x32_f16(a, bfr, acc[nb], 0, 0, 0);
    }
  }

  float dv[4];
#pragma unroll
  for (int r = 0; r < 4; ++r) {
    int grow = row0 + w * 16 + hi * 4 + r;
    dv[r] = dis[min(grow, n - 1)];
  }
  __syncthreads();  // all A-reads done before reusing xsb as staging
#pragma unroll
  for (int nb = 0; nb < 8; ++nb)
#pragma unroll
    for (int r = 0; r < 4; ++r) {
      int srow = w * 16 + hi * 4 + r;
      *(_Float16*)(xsb + swz(srow, (nb * 16 + l15) * 2)) = (_Float16)(acc[nb][r] * dv[r]);
    }
  __syncthreads();
#pragma unroll
  for (int i = tid; i < 64 * FEAT / 8; i += 256) {
    int row = row0 + (i >> 4);
    if (row < n)
      *(uint4*)&Hs_out[(size_t)row * FEAT + (i & 15) * 8] =
          *(const uint4*)(xsb + swz(i >> 4, (i & 15) * 16));
  }
}

// out(f16) = relu(dis[i] * (Hs[i] + sum Hs[src]) + b) — standalone (layer 2)
__global__ void __launch_bounds__(256) agg_kernel(const h8* __restrict__ Hs,
                                                  const int* __restrict__ csr,
                                                  const int* __restrict__ off,
                                                  const float* __restrict__ dis,
                                                  const float* __restrict__ b,
                                                  h8* __restrict__ out, int n) {
  int wave = threadIdx.x >> 6;
  int lane = threadIdx.x & 63;
  int grp = lane >> 4, lig = lane & 15;
  int node = blockIdx.x * 4 + wave;
  if (node >= n) return;
  int s = off[node];
  int e = off[node + 1];

  float acc[8];
  if (grp == 0) {
    h8 v = Hs[(size_t)node * 16 + lig];  // self-loop term
#pragma unroll
    for (int j = 0; j < 8; ++j) acc[j] = (float)v[j];
  } else {
#pragma unroll
    for (int j = 0; j < 8; ++j) acc[j] = 0.f;
  }

  for (int k = s; k < e; k += 16) {
    int k0 = k + grp, k1 = k0 + 4, k2 = k0 + 8, k3 = k0 + 12;
    int i0 = (k0 < e) ? csr[k0] : -1;
    int i1 = (k1 < e) ? csr[k1] : -1;
    int i2 = (k2 < e) ? csr[k2] : -1;
    int i3 = (k3 < e) ? csr[k3] : -1;
    h8 v0 = Hs[(size_t)max(i0, 0) * 16 + lig];
    h8 v1 = Hs[(size_t)max(i1, 0) * 16 + lig];
    h8 v2 = Hs[(size_t)max(i2, 0) * 16 + lig];
    h8 v3 = Hs[(size_t)max(i3, 0) * 16 + lig];
    if (i0 >= 0) {
#pragma unroll
      for (int j = 0; j < 8; ++j) acc[j] += (float)v0[j];
    }
    if (i1 >= 0) {
#pragma unroll
      for (int j = 0; j < 8; ++j) acc[j] += (float)v1[j];
    }
    if (i2 >= 0) {
#pragma unroll
      for (int j = 0; j < 8; ++j) acc[j] += (float)v2[j];
    }
    if (i3 >= 0) {
#pragma unroll
      for (int j = 0; j < 8; ++j) acc[j] += (float)v3[j];
    }
  }

#pragma unroll
  for (int j = 0; j < 8; ++j) {
    acc[j] += __shfl_xor(acc[j], 16);
    acc[j] += __shfl_xor(acc[j], 32);
  }

  if (grp == 0) {
    float d = dis[node];
    float4 b0 = ((const float4*)b)[lig * 2];
    float4 b1 = ((const float4*)b)[lig * 2 + 1];
    h8 o;
    o[0] = (_Float16)fmaxf(fmaf(d, acc[0], b0.x), 0.f);
    o[1] = (_Float16)fmaxf(fmaf(d, acc[1], b0.y), 0.f);
    o[2] = (_Float16)fmaxf(fmaf(d, acc[2], b0.z), 0.f);
    o[3] = (_Float16)fmaxf(fmaf(d, acc[3], b0.w), 0.f);
    o[4] = (_Float16)fmaxf(fmaf(d, acc[4], b1.x), 0.f);
    o[5] = (_Float16)fmaxf(fmaf(d, acc[5], b1.y), 0.f);
    o[6] = (_Float16)fmaxf(fmaf(d, acc[6], b1.z), 0.f);
    o[7] = (_Float16)fmaxf(fmaf(d, acc[7], b1.w), 0.f);
    out[(size_t)node * 16 + lig] = o;
  }
}

// graph boundaries from sorted batch
__global__ void bounds_kernel(const int* __restrict__ batch, int* __restrict__ gstart,
                              int n, int g) {
  int i = blockIdx.x * 256 + threadIdx.x;
  if (i >= n) return;
  int bi = batch[i];
  int bp = (i == 0) ? -1 : batch[i - 1];
  for (int q = bp + 1; q <= bi; ++q) gstart[q] = i;
  if (i == n - 1) {
    for (int q = bi + 1; q <= g; ++q) gstart[q] = n;
  }
}

// mean-pool per graph (f16 input) + linear(128->10) + log_softmax
__global__ void __launch_bounds__(128) pool_kernel(const __half* __restrict__ h,
                                                   const int* __restrict__ gstart,
                                                   const float* __restrict__ lw,
                                                   const float* __restrict__ lb,
                                                   float* __restrict__ out) {
  int g = blockIdx.x;
  int t = threadIdx.x;
  int s = gstart[g];
  int e = gstart[g + 1];
  float a0 = 0.f, a1 = 0.f, a2 = 0.f, a3 = 0.f;
  int i = s;
  for (; i + 4 <= e; i += 4) {
    a0 += __half2float(h[(size_t)i * FEAT + t]);
    a1 += __half2float(h[(size_t)(i + 1) * FEAT + t]);
    a2 += __half2float(h[(size_t)(i + 2) * FEAT + t]);
    a3 += __half2float(h[(size_t)(i + 3) * FEAT + t]);
  }
  for (; i < e; ++i) a0 += __half2float(h[(size_t)i * FEAT + t]);
  float acc = a0 + a1 + a2 + a3;
  float cnt = (float)(e - s);
  float pooled = acc / fmaxf(cnt, 1.f);
  __shared__ float lds[FEAT];
  __shared__ float logits[NCLASS];
  lds[t] = pooled;
  __syncthreads();
  if (t < NCLASS) {
    float z = lb[t];
    for (int k = 0; k < FEAT; ++k) z += lds[k] * lw[k * NCLASS + t];
    logits[t] = z;
  }
  __syncthreads();
  if (t < NCLASS) {
    float m = logits[0];
#pragma unroll
    for (int c = 1; c < NCLASS; ++c) m = fmaxf(m, logits[c]);
    float ssum = 0.f;
#pragma unroll
    for (int c = 0; c < NCLASS; ++c) ssum += expf(logits[c] - m);
    out[(size_t)g * NCLASS + t] = logits[t] - m - logf(ssum);
  }
}

extern "C" void kernel_launch(void* const* d_in, const int* in_sizes, int n_in,
                              void* d_out, int out_size, void* d_ws, size_t ws_size,
                              hipStream_t stream) {
  const float* x = (const float*)d_in[0];
  const int* ei = (const int*)d_in[1];
  const int* batch = (const int*)d_in[2];
  const float* W0 = (const float*)d_in[3];
  const float* b0 = (const float*)d_in[4];
  const float* W1 = (const float*)d_in[5];
  const float* b1 = (const float*)d_in[6];
  const float* W2 = (const float*)d_in[7];
  const float* b2 = (const float*)d_in[8];
  const float* lw = (const float*)d_in[9];
  const float* lb = (const float*)d_in[10];

  int n = in_sizes[2];        // 50000 nodes
  int ne = in_sizes[1] / 2;   // 800000 edges
  int g = out_size / NCLASS;  // 512 graphs
  int nb = (n + 127) >> 7;    // dst buckets (391)
  int hblocks = 120;
  int epb = (ne + hblocks - 1) / hblocks;
  int wtblocks = (3 * FEAT * FEAT + 255) / 256;  // 192

  char* ws = (char*)d_ws;
  size_t p = 0;
  auto alloc = [&](size_t bytes) {
    size_t cur = p;
    p += (bytes + 255) & ~(size_t)255;
    return cur;
  };
  int* off = (int*)(ws + alloc((size_t)(n + 1) * 4));
  int* csr = (int*)(ws + alloc((size_t)ne * 4));
  int* bhist = (int*)(ws + alloc((size_t)NB_MAX * 4));
  int* bstart = (int*)(ws + alloc((size_t)(NB_MAX + 1) * 4));
  int* bcur = (int*)(ws + alloc((size_t)NB_MAX * 4));
  int* gstart = (int*)(ws + alloc((size_t)(g + 1) * 4));
  float* dis = (float*)(ws + alloc((size_t)n * 4));
  unsigned* buf = (unsigned*)(ws + alloc((size_t)ne * 4));
  _Float16* Wt = (_Float16*)(ws + alloc((size_t)3 * FEAT * FEAT * 2));
  _Float16* HA = (_Float16*)(ws + alloc((size_t)n * FEAT * 2));
  _Float16* HB = (_Float16*)(ws + alloc((size_t)n * FEAT * 2));

  hipMemsetAsync(bhist, 0, NB_MAX * 4, stream);

  hist_wt_kernel<<<hblocks + wtblocks, 256, 0, stream>>>(ei, bhist, ne, nb, epb, hblocks,
                                                         W0, W1, W2, Wt);
  bscan_kernel<<<1, 512, 0, stream>>>(bhist, bstart, bcur, off, nb, n, ne);
  scatter_kernel<<<hblocks, 256, 0, stream>>>(ei, bcur, buf, ne, nb, epb);
  bucket_build_kernel<<<nb, 256, 0, stream>>>(buf, bstart, off, csr, dis, n);

  int gblocks = (n + 63) / 64;
  // layer 0: X(f32) @ W0 * dis -> HA
  gemm_mfma_kernel<true><<<gblocks, 256, 0, stream>>>(x, Wt, dis, HA, n);
  // layer 0 agg + layer 1 gemm: HA -> HB
  fused_kernel<<<gblocks, 256, 0, stream>>>((const h8*)HA, csr, off, dis, b0,
                                            Wt + (size_t)1 * FEAT * FEAT, HB, n);
  // layer 1 agg + layer 2 gemm: HB -> HA
  fused_kernel<<<gblocks, 256, 0, stream>>>((const h8*)HB, csr, off, dis, b1,
                                            Wt + (size_t)2 * FEAT * FEAT, HA, n);
  // layer 2 agg: HA -> HB (pool input)
  agg_kernel<<<(n + 3) / 4, 256, 0, stream>>>((const h8*)HA, csr, off, dis, b2, (h8*)HB, n);

  bounds_kernel<<<(n + 255) / 256, 256, 0, stream>>>(batch, gstart, n, g);
  pool_kernel<<<g, 128, 0, stream>>>((const __half*)HB, gstart, lw, lb, (float*)d_out);
}